// Round 1
// baseline (15436.894 us; speedup 1.0000x reference)
//
#include <hip/hip_runtime.h>

// resFAN pipeline, all-f32 correctness-first implementation.
// Key algebraic simplification (exact): k = f*rowsum(wB)+bB is rank-1 over the
// softmax axis, so att[b,i,j] = exp(A_i f_j - M_i)/Z_i with A = u.x + c0,
// u_i = sum_c rowsum(wB)_c wA[c,i].  The bB/bA terms shift energy by a
// constant over the softmax axis and cancel exactly.
//
// ws layout (floats):
//   fv  @ 0         : 16,777,216   v (later reused as conv ping-pong)
//   fy  @ 16777216  : 16,777,216   y = gamma*out + x (later scan ping-pong)
//   sm  @ 33554432  : A(16384) M(16384) invZ(16384) u(1024) s(128) c0(4) fstat(8)
// total ~128.3 MB

#define NPIX 4096

// ---------------- small prep kernels ----------------

__global__ void rf_s(const float* __restrict__ wB, const float* __restrict__ bA,
                     float* __restrict__ s_out, float* __restrict__ c0_out) {
  int c = threadIdx.x;  // 128 threads
  const float* row = wB + (size_t)c * 1024;
  float acc = 0.f;
  for (int i = 0; i < 1024; ++i) acc += row[i];
  s_out[c] = acc;
  __shared__ float sh[128];
  sh[c] = acc * bA[c];
  __syncthreads();
  for (int off = 64; off > 0; off >>= 1) {
    if (c < off) sh[c] += sh[c + off];
    __syncthreads();
  }
  if (c == 0) c0_out[0] = sh[0];
}

__global__ void rf_u(const float* __restrict__ wA, const float* __restrict__ s,
                     float* __restrict__ u) {
  int i = blockIdx.x * 256 + threadIdx.x;  // 1024 total
  float acc = 0.f;
  for (int c = 0; c < 128; ++c) acc += s[c] * wA[(size_t)c * 1024 + i];
  u[i] = acc;
}

__global__ void rf_fstat(const float* __restrict__ in, float* __restrict__ fstat) {
  int b = blockIdx.x;
  int t = threadIdx.x;
  const float* f = in + ((size_t)b * 1025 + 1024) * NPIX;
  float mx = -1e30f, mn = 1e30f;
  for (int j = t; j < NPIX; j += 256) {
    float v = f[j];
    mx = fmaxf(mx, v);
    mn = fminf(mn, v);
  }
  __shared__ float smx[256], smn[256];
  smx[t] = mx; smn[t] = mn;
  __syncthreads();
  for (int off = 128; off > 0; off >>= 1) {
    if (t < off) {
      smx[t] = fmaxf(smx[t], smx[t + off]);
      smn[t] = fminf(smn[t], smn[t + off]);
    }
    __syncthreads();
  }
  if (t == 0) { fstat[b] = smx[0]; fstat[4 + b] = smn[0]; }
}

__global__ __launch_bounds__(256) void rf_A(const float* __restrict__ in,
                                            const float* __restrict__ u,
                                            const float* __restrict__ c0p,
                                            const float* __restrict__ fst,
                                            float* __restrict__ A, float* __restrict__ M) {
  __shared__ float ul[1024];
  int b = blockIdx.y;
  int n = blockIdx.x * 256 + threadIdx.x;
  for (int s = threadIdx.x; s < 1024; s += 256) ul[s] = u[s];
  __syncthreads();
  const float* xp = in + (size_t)b * 1025 * NPIX + n;
  float acc = c0p[0];
#pragma unroll 8
  for (int i = 0; i < 1024; ++i) acc = fmaf(ul[i], xp[(size_t)i * NPIX], acc);
  A[b * NPIX + n] = acc;
  M[b * NPIX + n] = fmaxf(acc * fst[b], acc * fst[4 + b]);
}

__global__ void rf_Z(const float* __restrict__ in, const float* __restrict__ A,
                     const float* __restrict__ M, float* __restrict__ iZ) {
  int idx = blockIdx.x * 4 + (threadIdx.x >> 6);  // (b,n) pair, 16384 total
  int lane = threadIdx.x & 63;
  int b = idx >> 12;
  const float* f = in + ((size_t)b * 1025 + 1024) * NPIX;
  float a = A[idx], m = M[idx];
  float acc = 0.f;
#pragma unroll 4
  for (int it = 0; it < 64; ++it) acc += __expf(a * f[lane + it * 64] - m);
  for (int off = 32; off > 0; off >>= 1) acc += __shfl_down(acc, off, 64);
  if (lane == 0) iZ[idx] = 1.0f / acc;
}

// ---------------- tiled GEMM: v = wC @ x + bC ----------------
// tile: 64 co x 256 n, 256 threads, micro 4x16, K chunk 16.

__global__ __launch_bounds__(256) void rf_vgemm(const float* __restrict__ in,
                                                const float* __restrict__ wC,
                                                const float* __restrict__ bC,
                                                float* __restrict__ v) {
  int nt = blockIdx.x, cot = blockIdx.y, b = blockIdx.z;
  int nb = nt * 256, cb = cot * 64;
  __shared__ float wl[16][68];
  __shared__ float xl[16][260];
  int tid = threadIdx.x;
  int cg = tid >> 4, ig = tid & 15;
  int c0 = cg * 4;
  float acc[4][16] = {};
  for (int k0 = 0; k0 < 1024; k0 += 16) {
#pragma unroll
    for (int s = 0; s < 4; ++s) {
      int idx = tid + s * 256;
      int c = idx >> 4, k = idx & 15;
      wl[k][c] = wC[(size_t)(cb + c) * 1024 + k0 + k];
    }
#pragma unroll
    for (int s = 0; s < 16; ++s)
      xl[s][tid] = in[((size_t)b * 1025 + k0 + s) * NPIX + nb + tid];
    __syncthreads();
#pragma unroll
    for (int j = 0; j < 16; ++j) {
      const float4 vv = *(const float4*)&wl[j][c0];
      const float* vf = (const float*)&vv;
#pragma unroll
      for (int m = 0; m < 4; ++m) {
        const float4 pp = *(const float4*)&xl[j][ig * 4 + m * 64];
        const float* pf = (const float*)&pp;
#pragma unroll
        for (int ii = 0; ii < 4; ++ii)
#pragma unroll
          for (int q = 0; q < 4; ++q)
            acc[ii][m * 4 + q] = fmaf(vf[ii], pf[q], acc[ii][m * 4 + q]);
      }
    }
    __syncthreads();
  }
#pragma unroll
  for (int ii = 0; ii < 4; ++ii) {
    int c = cb + c0 + ii;
    float bv = bC[c];
    float* vp = v + ((size_t)b * 1024 + c) * NPIX + nb;
#pragma unroll
    for (int m = 0; m < 4; ++m) {
      int col = ig * 4 + m * 64;
#pragma unroll
      for (int q = 0; q < 4; ++q) vp[col + q] = acc[ii][m * 4 + q] + bv;
    }
  }
}

// ---------------- fused attention out-GEMM + residual ----------------
// out[b,c,i] = sum_j v[b,c,j] * exp(A_i f_j - M_i)*invZ_i ; y = gamma*out + x
// tile: 64 c x 256 i, K = j (4096) in chunks of 16; p-tile computed on the fly.

__global__ __launch_bounds__(256) void rf_att(const float* __restrict__ in,
                                              const float* __restrict__ v,
                                              const float* __restrict__ Aarr,
                                              const float* __restrict__ Marr,
                                              const float* __restrict__ iZ,
                                              const float* __restrict__ gptr,
                                              float* __restrict__ y) {
  int it = blockIdx.x, ct = blockIdx.y, b = blockIdx.z;
  int ib = it * 256, cb = ct * 64;
  __shared__ float vl[16][68];
  __shared__ float pl[16][260];
  int tid = threadIdx.x;
  int cg = tid >> 4, ig = tid & 15;
  int c0 = cg * 4;
  float av = Aarr[b * NPIX + ib + tid];
  float mv = Marr[b * NPIX + ib + tid];
  float pz = iZ[b * NPIX + ib + tid];
  const float* f = in + ((size_t)b * 1025 + 1024) * NPIX;
  float acc[4][16] = {};
  for (int j0 = 0; j0 < NPIX; j0 += 16) {
#pragma unroll
    for (int s = 0; s < 4; ++s) {
      int idx = tid + s * 256;
      int c = idx >> 4, j = idx & 15;
      vl[j][c] = v[((size_t)b * 1024 + cb + c) * NPIX + j0 + j];
    }
#pragma unroll
    for (int s = 0; s < 16; ++s) {
      float fj = f[j0 + s];  // wave-uniform
      pl[s][tid] = __expf(av * fj - mv) * pz;
    }
    __syncthreads();
#pragma unroll
    for (int j = 0; j < 16; ++j) {
      const float4 vv = *(const float4*)&vl[j][c0];
      const float* vf = (const float*)&vv;
#pragma unroll
      for (int m = 0; m < 4; ++m) {
        const float4 pp = *(const float4*)&pl[j][ig * 4 + m * 64];
        const float* pf = (const float*)&pp;
#pragma unroll
        for (int ii = 0; ii < 4; ++ii)
#pragma unroll
          for (int q = 0; q < 4; ++q)
            acc[ii][m * 4 + q] = fmaf(vf[ii], pf[q], acc[ii][m * 4 + q]);
      }
    }
    __syncthreads();
  }
  float g = gptr[0];
#pragma unroll
  for (int ii = 0; ii < 4; ++ii) {
    int c = cb + c0 + ii;
    const float* xp = in + ((size_t)b * 1025 + c) * NPIX + ib;
    float* yp = y + ((size_t)b * 1024 + c) * NPIX + ib;
#pragma unroll
    for (int m = 0; m < 4; ++m) {
      int col = ig * 4 + m * 64;
#pragma unroll
      for (int q = 0; q < 4; ++q)
        yp[col + q] = g * acc[ii][m * 4 + q] + xp[col + q];
    }
  }
}

// ---------------- dilated 3x3 conv (dilation 2, pad 2) + bias + relu --------
// tile: 32 co x (4 rows x 64 w), 256 threads, micro 4co x 8w, CI chunks of 8.

__global__ __launch_bounds__(256) void rf_conv(const float* __restrict__ src,
                                               float* __restrict__ dst,
                                               const float* __restrict__ wconv,
                                               const float* __restrict__ bias,
                                               int CI, int CO) {
  int cot = blockIdx.x;  // CO/32
  int rt = blockIdx.y;   // 16 row tiles
  int b = blockIdx.z;
  int h0 = rt * 4;
  int cobase = cot * 32;
  __shared__ float xs[8][8][74];     // [ci][row][w+2 padded], rows h0-2..h0+5
  __shared__ float wsld[8][9][32];   // [ci][kh*3+kw][co]
  int tid = threadIdx.x;
  int cg = tid >> 5;        // 0..7 -> 4 co each
  int pg = tid & 31;
  int r = pg >> 3;          // 0..3 output row
  int w0 = (pg & 7) * 8;    // 8 w each
  float acc[4][8] = {};
  for (int ci0 = 0; ci0 < CI; ci0 += 8) {
    for (int s = tid; s < 8 * 8 * 74; s += 256) {
      int ci = s / 592;
      int rem = s - ci * 592;
      int r8 = rem / 74;
      int wi = rem - r8 * 74;
      int gh = h0 - 2 + r8;
      int gw = wi - 2;
      float vv = 0.f;
      if (gh >= 0 && gh < 64 && gw >= 0 && gw < 64)
        vv = src[(((size_t)b * CI + ci0 + ci) * 64 + gh) * 64 + gw];
      xs[ci][r8][wi] = vv;
    }
    for (int s = tid; s < 2304; s += 256) {
      int co = s / 72;
      int rem = s - co * 72;
      int ci = rem / 9;
      int k = rem - ci * 9;
      wsld[ci][k][co] = wconv[((size_t)(cobase + co) * CI + ci0 + ci) * 9 + k];
    }
    __syncthreads();
#pragma unroll
    for (int ci = 0; ci < 8; ++ci) {
#pragma unroll
      for (int kh = 0; kh < 3; ++kh) {
        const float* xrow = &xs[ci][r + 2 * kh][w0];
        float xr[12];
#pragma unroll
        for (int m = 0; m < 6; ++m) {
          float2 t2 = *(const float2*)&xrow[2 * m];
          xr[2 * m] = t2.x; xr[2 * m + 1] = t2.y;
        }
#pragma unroll
        for (int kw = 0; kw < 3; ++kw) {
          const float4 wv = *(const float4*)&wsld[ci][kh * 3 + kw][cg * 4];
          const float* wf = (const float*)&wv;
#pragma unroll
          for (int ii = 0; ii < 4; ++ii)
#pragma unroll
            for (int jj = 0; jj < 8; ++jj)
              acc[ii][jj] = fmaf(wf[ii], xr[jj + 2 * kw], acc[ii][jj]);
        }
      }
    }
    __syncthreads();
  }
#pragma unroll
  for (int ii = 0; ii < 4; ++ii) {
    int co = cobase + cg * 4 + ii;
    float bv = bias[co];
    float* dp = dst + (((size_t)b * CO + co) * 64 + h0 + r) * 64 + w0;
#pragma unroll
    for (int jj = 0; jj < 8; ++jj) dp[jj] = fmaxf(acc[ii][jj] + bv, 0.f);
  }
}

// ---------------- recurrent scan pass (conv1d k=9 pad 4 over 'pos') --------
// One block per batch.  tid = co*8 + cig; each thread holds w[co][cig*8+cl][k]
// in registers, computes partial sums over its 8 ci for 32 positions, then
// __shfl_xor-reduces over the 8 partner lanes.

__global__ __launch_bounds__(512) void rf_scan(const float* __restrict__ src,
                                               float* __restrict__ dst,
                                               const float* __restrict__ wconv,
                                               const float* __restrict__ bias,
                                               int dir) {
  int b = blockIdx.x;
  __shared__ float carry[64][74];  // [ci][pos+4], pads [0..3] and [68..73] = 0
  int tid = threadIdx.x;
  int co = tid >> 3;
  int cig = tid & 7;
  float wreg[72];
#pragma unroll
  for (int cl = 0; cl < 8; ++cl)
#pragma unroll
    for (int k = 0; k < 9; ++k)
      wreg[cl * 9 + k] = wconv[((size_t)co * 64 + cig * 8 + cl) * 9 + k];
  float bv = bias[co];
  for (int s = tid; s < 64 * 74; s += 512) {
    int ci = s / 74;
    int p = s - ci * 74;
    if (p < 4 || p >= 68) carry[ci][p] = 0.f;
  }
  {
    int step = (dir > 0) ? 0 : 63;
    const float* sp = src + (((size_t)b * 64 + co) * 64 + step) * 64;
    float* dp = dst + (((size_t)b * 64 + co) * 64 + step) * 64;
#pragma unroll
    for (int m = 0; m < 8; ++m) {
      int pos = cig * 8 + m;
      float v = sp[pos];
      dp[pos] = v;
      carry[co][4 + pos] = v;
    }
  }
  __syncthreads();
  float val0[4], val1[4];
  for (int s = 1; s < 64; ++s) {
    int step = (dir > 0) ? s : 63 - s;
    const float* sp = src + (((size_t)b * 64 + co) * 64 + step) * 64;
    float* dp = dst + (((size_t)b * 64 + co) * 64 + step) * 64;
#pragma unroll
    for (int half = 0; half < 2; ++half) {
      float accv[32];
#pragma unroll
      for (int p = 0; p < 32; ++p) accv[p] = 0.f;
#pragma unroll
      for (int cl = 0; cl < 8; ++cl) {
        int ci = cig * 8 + cl;
        float xr[40];
#pragma unroll
        for (int m = 0; m < 20; ++m) {
          float2 t2 = *(const float2*)&carry[ci][half * 32 + 2 * m];
          xr[2 * m] = t2.x; xr[2 * m + 1] = t2.y;
        }
#pragma unroll
        for (int k = 0; k < 9; ++k) {
          float wv = wreg[cl * 9 + k];
#pragma unroll
          for (int p = 0; p < 32; ++p) accv[p] = fmaf(wv, xr[p + k], accv[p]);
        }
      }
#pragma unroll
      for (int m = 1; m < 8; m <<= 1)
#pragma unroll
        for (int p = 0; p < 32; ++p) accv[p] += __shfl_xor(accv[p], m, 64);
      float* vout = half ? val1 : val0;
#pragma unroll
      for (int q = 0; q < 4; ++q) {
        int pos = half * 32 + cig * 4 + q;
        vout[q] = fmaxf(accv[cig * 4 + q] + bv, 0.f) + sp[pos];
      }
    }
    __syncthreads();
#pragma unroll
    for (int q = 0; q < 4; ++q) {
      int p0 = cig * 4 + q;
      int p1 = 32 + cig * 4 + q;
      carry[co][4 + p0] = val0[q]; dp[p0] = val0[q];
      carry[co][4 + p1] = val1[q]; dp[p1] = val1[q];
    }
    __syncthreads();
  }
}

// ---------------- transpose last two dims (64x64) per (b,c) ----------------

__global__ void rf_transpose(const float* __restrict__ src, float* __restrict__ dst) {
  int bc = blockIdx.x;  // 256
  __shared__ float tl[64][65];
  int tid = threadIdx.x;
  const float* sp = src + (size_t)bc * 4096;
  float* dp = dst + (size_t)bc * 4096;
  for (int s = tid; s < 4096; s += 256) {
    int h = s >> 6, w = s & 63;
    tl[w][h] = sp[s];
  }
  __syncthreads();
  for (int s = tid; s < 4096; s += 256) dp[s] = tl[s >> 6][s & 63];
}

// ---------------- final 1x1 conv + relu + 8x8 upsample ----------------
// input t layout [b][c][w][h] (transposed), output [b][512][512]

__global__ void rf_final(const float* __restrict__ t, const float* __restrict__ ow,
                         const float* __restrict__ ob, float* __restrict__ out) {
  int b = blockIdx.y;
  int s = blockIdx.x * 256 + threadIdx.x;  // 0..4095
  int w = s >> 6, h = s & 63;
  float acc = ob[0];
  for (int c = 0; c < 64; ++c)
    acc += ow[c] * t[(((size_t)b * 64 + c) * 64 + w) * 64 + h];
  acc = fmaxf(acc, 0.f);
  float4 vv = make_float4(acc, acc, acc, acc);
  for (int dy = 0; dy < 8; ++dy) {
    float* dp = out + ((size_t)b * 512 + h * 8 + dy) * 512 + w * 8;
    *(float4*)dp = vv;
    *(float4*)(dp + 4) = vv;
  }
}

// ---------------- launch ----------------

extern "C" void kernel_launch(void* const* d_in, const int* in_sizes, int n_in,
                              void* d_out, int out_size, void* d_ws, size_t ws_size,
                              hipStream_t stream) {
  const float* in    = (const float*)d_in[0];
  const float* wA    = (const float*)d_in[1];
  const float* bA    = (const float*)d_in[2];
  const float* wB    = (const float*)d_in[3];
  const float* wC    = (const float*)d_in[5];
  const float* bC    = (const float*)d_in[6];
  const float* gamma = (const float*)d_in[7];
  const float* bw1 = (const float*)d_in[8];  const float* bb1 = (const float*)d_in[9];
  const float* bw2 = (const float*)d_in[10]; const float* bb2 = (const float*)d_in[11];
  const float* bw3 = (const float*)d_in[12]; const float* bb3 = (const float*)d_in[13];
  const float* bw4 = (const float*)d_in[14]; const float* bb4 = (const float*)d_in[15];
  const float* bw5 = (const float*)d_in[16]; const float* bb5 = (const float*)d_in[17];
  const float* bw6 = (const float*)d_in[18]; const float* bb6 = (const float*)d_in[19];
  const float* du_w = (const float*)d_in[20]; const float* du_b = (const float*)d_in[21];
  const float* lr_w = (const float*)d_in[22]; const float* lr_b = (const float*)d_in[23];
  const float* ow   = (const float*)d_in[24]; const float* ob   = (const float*)d_in[25];
  float* out = (float*)d_out;
  float* ws = (float*)d_ws;

  float* fv = ws;                    // 16,777,216 floats
  float* fy = ws + 16777216;         // 16,777,216 floats
  float* sm = ws + 33554432;
  float* A_  = sm;
  float* M_  = sm + 16384;
  float* iZ  = sm + 32768;
  float* u_  = sm + 49152;
  float* s_  = sm + 50176;
  float* c0_ = sm + 50304;
  float* fst = sm + 50308;

  rf_s<<<1, 128, 0, stream>>>(wB, bA, s_, c0_);
  rf_u<<<4, 256, 0, stream>>>(wA, s_, u_);
  rf_fstat<<<4, 256, 0, stream>>>(in, fst);
  rf_A<<<dim3(16, 4), 256, 0, stream>>>(in, u_, c0_, fst, A_, M_);
  rf_Z<<<4096, 256, 0, stream>>>(in, A_, M_, iZ);
  rf_vgemm<<<dim3(16, 16, 4), 256, 0, stream>>>(in, wC, bC, fv);
  rf_att<<<dim3(16, 16, 4), 256, 0, stream>>>(in, fv, A_, M_, iZ, gamma, fy);

  float* c1 = fv;             // 4*512*4096
  float* c2 = fv + 8388608;
  rf_conv<<<dim3(16, 16, 4), 256, 0, stream>>>(fy, c1, bw1, bb1, 1024, 512);
  rf_conv<<<dim3(16, 16, 4), 256, 0, stream>>>(c1, c2, bw2, bb2, 512, 512);
  rf_conv<<<dim3(16, 16, 4), 256, 0, stream>>>(c2, c1, bw3, bb3, 512, 512);
  rf_conv<<<dim3(8, 16, 4), 256, 0, stream>>>(c1, c2, bw4, bb4, 512, 256);
  rf_conv<<<dim3(4, 16, 4), 256, 0, stream>>>(c2, c1, bw5, bb5, 256, 128);
  rf_conv<<<dim3(2, 16, 4), 256, 0, stream>>>(c1, c2, bw6, bb6, 128, 64);

  float* t0 = fy;             // 1,048,576 floats each
  float* t1 = fy + 1048576;
  rf_scan<<<4, 512, 0, stream>>>(c2, t0, du_w, du_b, +1);
  rf_scan<<<4, 512, 0, stream>>>(t0, t1, du_w, du_b, -1);
  rf_transpose<<<256, 256, 0, stream>>>(t1, t0);
  rf_scan<<<4, 512, 0, stream>>>(t0, t1, lr_w, lr_b, +1);
  rf_scan<<<4, 512, 0, stream>>>(t1, t0, lr_w, lr_b, -1);
  rf_final<<<dim3(16, 4), 256, 0, stream>>>(t0, ow, ob, out);
}

// Round 2
// 10310.051 us; speedup vs baseline: 1.4973x; 1.4973x over previous
//
#include <hip/hip_runtime.h>

// resFAN pipeline, round 2: dilated convs moved to MFMA (split-fp16 x3 scheme).
// Attention math unchanged (rank-1 key -> att[i,j] = exp(A_i f_j - M_i)/Z_i).
//
// Precision scheme for convs: activations stored as fp16 pair (hi,lo) of 16*y;
// weights as fp16 pair of 256*w (per-tap matrices [9][CO][CI]).  acc_f32 +=
// Ah*Wh + Ah*Wl + Al*Wh  (lo*lo dropped, rel ~2^-22); epilogue * 1/4096.
//
// ws layout (f32 slots), total 33,604,744 (same as round 1):
//  R0 [0, 16777216): fv (f32 v) -> then w1|c1|w3 -> c3 -> w5|c5|w6 -> tin|t0|t1
//  R1 [16777216, 33554432): yH|yL -> w2|c2|w4|c4
//  SM [33554432, 33604744): stats

#define NPIX 4096

typedef _Float16 f16;
typedef _Float16 f16x8 __attribute__((ext_vector_type(8)));
typedef float f32x4 __attribute__((ext_vector_type(4)));

__device__ inline void async16(const void* g, void* l) {
  __builtin_amdgcn_global_load_lds(
      (const __attribute__((address_space(1))) unsigned int*)g,
      (__attribute__((address_space(3))) unsigned int*)l, 16, 0, 0);
}

// ---------------- small prep kernels ----------------

__global__ void rf_s(const float* __restrict__ wB, const float* __restrict__ bA,
                     float* __restrict__ s_out, float* __restrict__ c0_out) {
  int c = threadIdx.x;  // 128 threads
  const float* row = wB + (size_t)c * 1024;
  float acc = 0.f;
  for (int i = 0; i < 1024; ++i) acc += row[i];
  s_out[c] = acc;
  __shared__ float sh[128];
  sh[c] = acc * bA[c];
  __syncthreads();
  for (int off = 64; off > 0; off >>= 1) {
    if (c < off) sh[c] += sh[c + off];
    __syncthreads();
  }
  if (c == 0) c0_out[0] = sh[0];
}

__global__ void rf_u(const float* __restrict__ wA, const float* __restrict__ s,
                     float* __restrict__ u) {
  int i = blockIdx.x * 256 + threadIdx.x;  // 1024 total
  float acc = 0.f;
  for (int c = 0; c < 128; ++c) acc += s[c] * wA[(size_t)c * 1024 + i];
  u[i] = acc;
}

__global__ void rf_fstat(const float* __restrict__ in, float* __restrict__ fstat) {
  int b = blockIdx.x;
  int t = threadIdx.x;
  const float* f = in + ((size_t)b * 1025 + 1024) * NPIX;
  float mx = -1e30f, mn = 1e30f;
  for (int j = t; j < NPIX; j += 256) {
    float v = f[j];
    mx = fmaxf(mx, v);
    mn = fminf(mn, v);
  }
  __shared__ float smx[256], smn[256];
  smx[t] = mx; smn[t] = mn;
  __syncthreads();
  for (int off = 128; off > 0; off >>= 1) {
    if (t < off) {
      smx[t] = fmaxf(smx[t], smx[t + off]);
      smn[t] = fminf(smn[t], smn[t + off]);
    }
    __syncthreads();
  }
  if (t == 0) { fstat[b] = smx[0]; fstat[4 + b] = smn[0]; }
}

__global__ __launch_bounds__(256) void rf_A(const float* __restrict__ in,
                                            const float* __restrict__ u,
                                            const float* __restrict__ c0p,
                                            const float* __restrict__ fst,
                                            float* __restrict__ A, float* __restrict__ M) {
  __shared__ float ul[1024];
  int b = blockIdx.y;
  int n = blockIdx.x * 256 + threadIdx.x;
  for (int s = threadIdx.x; s < 1024; s += 256) ul[s] = u[s];
  __syncthreads();
  const float* xp = in + (size_t)b * 1025 * NPIX + n;
  float acc = c0p[0];
#pragma unroll 8
  for (int i = 0; i < 1024; ++i) acc = fmaf(ul[i], xp[(size_t)i * NPIX], acc);
  A[b * NPIX + n] = acc;
  M[b * NPIX + n] = fmaxf(acc * fst[b], acc * fst[4 + b]);
}

__global__ void rf_Z(const float* __restrict__ in, const float* __restrict__ A,
                     const float* __restrict__ M, float* __restrict__ iZ) {
  int idx = blockIdx.x * 4 + (threadIdx.x >> 6);  // (b,n) pair, 16384 total
  int lane = threadIdx.x & 63;
  int b = idx >> 12;
  const float* f = in + ((size_t)b * 1025 + 1024) * NPIX;
  float a = A[idx], m = M[idx];
  float acc = 0.f;
#pragma unroll 4
  for (int it = 0; it < 64; ++it) acc += __expf(a * f[lane + it * 64] - m);
  for (int off = 32; off > 0; off >>= 1) acc += __shfl_down(acc, off, 64);
  if (lane == 0) iZ[idx] = 1.0f / acc;
}

// ---------------- tiled GEMM: v = wC @ x + bC ----------------

__global__ __launch_bounds__(256) void rf_vgemm(const float* __restrict__ in,
                                                const float* __restrict__ wC,
                                                const float* __restrict__ bC,
                                                float* __restrict__ v) {
  int nt = blockIdx.x, cot = blockIdx.y, b = blockIdx.z;
  int nb = nt * 256, cb = cot * 64;
  __shared__ float wl[16][68];
  __shared__ float xl[16][260];
  int tid = threadIdx.x;
  int cg = tid >> 4, ig = tid & 15;
  int c0 = cg * 4;
  float acc[4][16] = {};
  for (int k0 = 0; k0 < 1024; k0 += 16) {
#pragma unroll
    for (int s = 0; s < 4; ++s) {
      int idx = tid + s * 256;
      int c = idx >> 4, k = idx & 15;
      wl[k][c] = wC[(size_t)(cb + c) * 1024 + k0 + k];
    }
#pragma unroll
    for (int s = 0; s < 16; ++s)
      xl[s][tid] = in[((size_t)b * 1025 + k0 + s) * NPIX + nb + tid];
    __syncthreads();
#pragma unroll
    for (int j = 0; j < 16; ++j) {
      const float4 vv = *(const float4*)&wl[j][c0];
      const float* vf = (const float*)&vv;
#pragma unroll
      for (int m = 0; m < 4; ++m) {
        const float4 pp = *(const float4*)&xl[j][ig * 4 + m * 64];
        const float* pf = (const float*)&pp;
#pragma unroll
        for (int ii = 0; ii < 4; ++ii)
#pragma unroll
          for (int q = 0; q < 4; ++q)
            acc[ii][m * 4 + q] = fmaf(vf[ii], pf[q], acc[ii][m * 4 + q]);
      }
    }
    __syncthreads();
  }
#pragma unroll
  for (int ii = 0; ii < 4; ++ii) {
    int c = cb + c0 + ii;
    float bv = bC[c];
    float* vp = v + ((size_t)b * 1024 + c) * NPIX + nb;
#pragma unroll
    for (int m = 0; m < 4; ++m) {
      int col = ig * 4 + m * 64;
#pragma unroll
      for (int q = 0; q < 4; ++q) vp[col + q] = acc[ii][m * 4 + q] + bv;
    }
  }
}

// ---------------- fused attention out-GEMM + residual -> split y ------------
// y = gamma*out + x ; stored channels-last as fp16 pair of 16*y.

__global__ __launch_bounds__(256) void rf_att(const float* __restrict__ in,
                                              const float* __restrict__ v,
                                              const float* __restrict__ Aarr,
                                              const float* __restrict__ Marr,
                                              const float* __restrict__ iZ,
                                              const float* __restrict__ gptr,
                                              f16* __restrict__ yH,
                                              f16* __restrict__ yL) {
  int it = blockIdx.x, ct = blockIdx.y, b = blockIdx.z;
  int ib = it * 256, cb = ct * 64;
  __shared__ float vl[16][68];
  __shared__ float pl[16][260];
  int tid = threadIdx.x;
  int cg = tid >> 4, ig = tid & 15;
  int c0 = cg * 4;
  float av = Aarr[b * NPIX + ib + tid];
  float mv = Marr[b * NPIX + ib + tid];
  float pz = iZ[b * NPIX + ib + tid];
  const float* f = in + ((size_t)b * 1025 + 1024) * NPIX;
  float acc[4][16] = {};
  for (int j0 = 0; j0 < NPIX; j0 += 16) {
#pragma unroll
    for (int s = 0; s < 4; ++s) {
      int idx = tid + s * 256;
      int c = idx >> 4, j = idx & 15;
      vl[j][c] = v[((size_t)b * 1024 + cb + c) * NPIX + j0 + j];
    }
#pragma unroll
    for (int s = 0; s < 16; ++s) {
      float fj = f[j0 + s];  // wave-uniform
      pl[s][tid] = __expf(av * fj - mv) * pz;
    }
    __syncthreads();
#pragma unroll
    for (int j = 0; j < 16; ++j) {
      const float4 vv = *(const float4*)&vl[j][c0];
      const float* vf = (const float*)&vv;
#pragma unroll
      for (int m = 0; m < 4; ++m) {
        const float4 pp = *(const float4*)&pl[j][ig * 4 + m * 64];
        const float* pf = (const float*)&pp;
#pragma unroll
        for (int ii = 0; ii < 4; ++ii)
#pragma unroll
          for (int q = 0; q < 4; ++q)
            acc[ii][m * 4 + q] = fmaf(vf[ii], pf[q], acc[ii][m * 4 + q]);
      }
    }
    __syncthreads();
  }
  float g = gptr[0];
#pragma unroll
  for (int ii = 0; ii < 4; ++ii) {
    int c = cb + c0 + ii;
    const float* xp = in + ((size_t)b * 1025 + c) * NPIX + ib;
#pragma unroll
    for (int m = 0; m < 4; ++m) {
      int col = ig * 4 + m * 64;
#pragma unroll
      for (int q = 0; q < 4; ++q) {
        float sv = 16.f * (g * acc[ii][m * 4 + q] + xp[col + q]);
        f16 hv = (f16)sv;
        size_t o = ((size_t)b * NPIX + ib + col + q) * 1024 + c;
        yH[o] = hv;
        yL[o] = (f16)(sv - (float)hv);
      }
    }
  }
}

// ---------------- weight split prep: [CO][CI][3][3] -> [9][CO][CI] hi/lo ----

__global__ void rf_wsplit(const float* __restrict__ w, f16* __restrict__ wh,
                          f16* __restrict__ wlo, int CO, int CI) {
  int idx = blockIdx.x * 256 + threadIdx.x;  // co*CI + ci
  if (idx >= CO * CI) return;
  int co = idx / CI, ci = idx - co * CI;
#pragma unroll
  for (int t = 0; t < 9; ++t) {
    float v = 256.0f * w[(size_t)idx * 9 + t];
    f16 h = (f16)v;
    size_t o = ((size_t)t * CO + co) * CI + ci;
    wh[o] = h;
    wlo[o] = (f16)(v - (float)h);
  }
}

// ---------------- MFMA dilated 3x3 conv (implicit GEMM, split fp16) --------
// x: [b][64][64][CI] fp16 hi/lo (scale 16); w: [9][CO][CI] hi/lo (scale 256).
// out: [b][64][64][CO] hi/lo (scale 16)  or  f32 NCHW (F32OUT).
// LDS layout chunk-major: [ci_chunk(4)][idx(BM|BN)][8 f16] -> conflict-free
// ds_read_b128 frags; staging via exec-masked global_load_lds width 16 over
// per-tap pre-zeroed slots (handles pad-2 boundaries).

template <int BM, int BN, bool F32OUT>
__global__ __launch_bounds__(256, 2) void rf_mconv(
    const f16* __restrict__ xh, const f16* __restrict__ xl,
    const f16* __restrict__ wh, const f16* __restrict__ wlo,
    const float* __restrict__ bias,
    f16* __restrict__ oh, f16* __restrict__ ol, float* __restrict__ of,
    int CI, int CO) {
  constexpr int ROWS = BM / 64;       // rows per pixel tile
  constexpr int TPI = 4096 / BM;      // tiles per image
  constexpr int NSA = BM / 64;        // staging chunks per thread (A)
  constexpr int NSB = BN / 64;        // (B)
  __shared__ f16 sAh[BM * 32], sAl[BM * 32], sBh[BN * 32], sBl[BN * 32];
  const int tid = threadIdx.x;
  const int blkpx = blockIdx.x;
  const int cob = blockIdx.y * BN;
  const int b = blkpx / TPI;
  const int h0 = (blkpx - b * TPI) * ROWS;

  const int pA = tid & (BM - 1);
  const int rA = pA >> 6, wpx = pA & 63;
  const int pB = tid & (BN - 1);

  const int wv = tid >> 6, lane = tid & 63;
  const int mrow = lane & 15, quad = lane >> 4;
  const int wm = (BN == 128) ? (wv & 1) * 64 : wv * 64;
  const int wn = (BN == 128) ? (wv >> 1) * 64 : 0;

  f32x4 acc[4][4];
#pragma unroll
  for (int i = 0; i < 4; ++i)
#pragma unroll
    for (int j = 0; j < 4; ++j) acc[i][j] = (f32x4){0.f, 0.f, 0.f, 0.f};

  const int KI = CI >> 5;
  for (int t = 0; t < 9; ++t) {
    const int dh = (t / 3) * 2 - 2, dw = (t - (t / 3) * 3) * 2 - 2;
    const int hin = h0 + rA + dh, win = wpx + dw;
    const bool val = ((unsigned)hin < 64u) && ((unsigned)win < 64u);
    const size_t apix = (((size_t)b * 64 + (val ? hin : 0)) * 64 + (val ? win : 0)) * CI;
    // zero A slots so exec-masked DMA leaves zeros for OOB pixels all tap long
#pragma unroll
    for (int s = 0; s < NSA; ++s) {
      int c = tid + 256 * s;
      *(int4*)&sAh[c * 8] = make_int4(0, 0, 0, 0);
      *(int4*)&sAl[c * 8] = make_int4(0, 0, 0, 0);
    }
    __syncthreads();
    const size_t wbase = ((size_t)t * CO + cob + pB) * CI;
    for (int k = 0; k < KI; ++k) {
      const int ci0 = k << 5;
      // stage A (activations)
#pragma unroll
      for (int s = 0; s < NSA; ++s) {
        const int cc = ((tid + 256 * s) / BM) & 3;
        const int lb = ((tid & ~63) + 256 * s) * 8;
        if (val) {
          size_t go = apix + ci0 + cc * 8;
          async16(xh + go, &sAh[lb]);
          async16(xl + go, &sAl[lb]);
        }
      }
      // stage B (weights)
#pragma unroll
      for (int s = 0; s < NSB; ++s) {
        const int cc = ((tid + 256 * s) / BN) & 3;
        const int lb = ((tid & ~63) + 256 * s) * 8;
        size_t go = wbase + ci0 + cc * 8;
        async16(wh + go, &sBh[lb]);
        async16(wlo + go, &sBl[lb]);
      }
      __syncthreads();
      f16x8 fah[4], fal[4], fbh[4], fbl[4];
#pragma unroll
      for (int mi = 0; mi < 4; ++mi) {
        int ix = (quad * BM + wm + mi * 16 + mrow) * 8;
        fah[mi] = *(const f16x8*)&sAh[ix];
        fal[mi] = *(const f16x8*)&sAl[ix];
      }
#pragma unroll
      for (int ni = 0; ni < 4; ++ni) {
        int ix = (quad * BN + wn + ni * 16 + mrow) * 8;
        fbh[ni] = *(const f16x8*)&sBh[ix];
        fbl[ni] = *(const f16x8*)&sBl[ix];
      }
#pragma unroll
      for (int mi = 0; mi < 4; ++mi)
#pragma unroll
        for (int ni = 0; ni < 4; ++ni)
          acc[mi][ni] = __builtin_amdgcn_mfma_f32_16x16x32_f16(fah[mi], fbh[ni], acc[mi][ni], 0, 0, 0);
#pragma unroll
      for (int mi = 0; mi < 4; ++mi)
#pragma unroll
        for (int ni = 0; ni < 4; ++ni)
          acc[mi][ni] = __builtin_amdgcn_mfma_f32_16x16x32_f16(fah[mi], fbl[ni], acc[mi][ni], 0, 0, 0);
#pragma unroll
      for (int mi = 0; mi < 4; ++mi)
#pragma unroll
        for (int ni = 0; ni < 4; ++ni)
          acc[mi][ni] = __builtin_amdgcn_mfma_f32_16x16x32_f16(fal[mi], fbh[ni], acc[mi][ni], 0, 0, 0);
      __syncthreads();
    }
  }
  // epilogue: descale, bias, relu, re-split (or f32 NCHW for scan input)
  const float inv = 1.0f / 4096.0f;
  float bvs[4];
#pragma unroll
  for (int ni = 0; ni < 4; ++ni) bvs[ni] = bias[cob + wn + ni * 16 + mrow];
#pragma unroll
  for (int mi = 0; mi < 4; ++mi) {
#pragma unroll
    for (int rg = 0; rg < 4; ++rg) {
      int px = wm + mi * 16 + quad * 4 + rg;
      int hh = h0 + (px >> 6), wwp = px & 63;
#pragma unroll
      for (int ni = 0; ni < 4; ++ni) {
        int co = cob + wn + ni * 16 + mrow;
        float vv = fmaxf(acc[mi][ni][rg] * inv + bvs[ni], 0.f);
        if (F32OUT) {
          of[(((size_t)b * CO + co) * 64 + hh) * 64 + wwp] = vv;
        } else {
          float sv = vv * 16.f;
          f16 hv = (f16)sv;
          size_t o = (((size_t)b * 64 + hh) * 64 + wwp) * CO + co;
          oh[o] = hv;
          ol[o] = (f16)(sv - (float)hv);
        }
      }
    }
  }
}

// ---------------- recurrent scan pass (conv1d k=9 pad 4 over 'pos') --------

__global__ __launch_bounds__(512) void rf_scan(const float* __restrict__ src,
                                               float* __restrict__ dst,
                                               const float* __restrict__ wconv,
                                               const float* __restrict__ bias,
                                               int dir) {
  int b = blockIdx.x;
  __shared__ float carry[64][74];
  int tid = threadIdx.x;
  int co = tid >> 3;
  int cig = tid & 7;
  float wreg[72];
#pragma unroll
  for (int cl = 0; cl < 8; ++cl)
#pragma unroll
    for (int k = 0; k < 9; ++k)
      wreg[cl * 9 + k] = wconv[((size_t)co * 64 + cig * 8 + cl) * 9 + k];
  float bv = bias[co];
  for (int s = tid; s < 64 * 74; s += 512) {
    int ci = s / 74;
    int p = s - ci * 74;
    if (p < 4 || p >= 68) carry[ci][p] = 0.f;
  }
  {
    int step = (dir > 0) ? 0 : 63;
    const float* sp = src + (((size_t)b * 64 + co) * 64 + step) * 64;
    float* dp = dst + (((size_t)b * 64 + co) * 64 + step) * 64;
#pragma unroll
    for (int m = 0; m < 8; ++m) {
      int pos = cig * 8 + m;
      float v = sp[pos];
      dp[pos] = v;
      carry[co][4 + pos] = v;
    }
  }
  __syncthreads();
  float val0[4], val1[4];
  for (int s = 1; s < 64; ++s) {
    int step = (dir > 0) ? s : 63 - s;
    const float* sp = src + (((size_t)b * 64 + co) * 64 + step) * 64;
    float* dp = dst + (((size_t)b * 64 + co) * 64 + step) * 64;
#pragma unroll
    for (int half = 0; half < 2; ++half) {
      float accv[32];
#pragma unroll
      for (int p = 0; p < 32; ++p) accv[p] = 0.f;
#pragma unroll
      for (int cl = 0; cl < 8; ++cl) {
        int ci = cig * 8 + cl;
        float xr[40];
#pragma unroll
        for (int m = 0; m < 20; ++m) {
          float2 t2 = *(const float2*)&carry[ci][half * 32 + 2 * m];
          xr[2 * m] = t2.x; xr[2 * m + 1] = t2.y;
        }
#pragma unroll
        for (int k = 0; k < 9; ++k) {
          float wv = wreg[cl * 9 + k];
#pragma unroll
          for (int p = 0; p < 32; ++p) accv[p] = fmaf(wv, xr[p + k], accv[p]);
        }
      }
#pragma unroll
      for (int m = 1; m < 8; m <<= 1)
#pragma unroll
        for (int p = 0; p < 32; ++p) accv[p] += __shfl_xor(accv[p], m, 64);
      float* vout = half ? val1 : val0;
#pragma unroll
      for (int q = 0; q < 4; ++q) {
        int pos = half * 32 + cig * 4 + q;
        vout[q] = fmaxf(accv[cig * 4 + q] + bv, 0.f) + sp[pos];
      }
    }
    __syncthreads();
#pragma unroll
    for (int q = 0; q < 4; ++q) {
      int p0 = cig * 4 + q;
      int p1 = 32 + cig * 4 + q;
      carry[co][4 + p0] = val0[q]; dp[p0] = val0[q];
      carry[co][4 + p1] = val1[q]; dp[p1] = val1[q];
    }
    __syncthreads();
  }
}

// ---------------- transpose last two dims (64x64) per (b,c) ----------------

__global__ void rf_transpose(const float* __restrict__ src, float* __restrict__ dst) {
  int bc = blockIdx.x;  // 256
  __shared__ float tl[64][65];
  int tid = threadIdx.x;
  const float* sp = src + (size_t)bc * 4096;
  float* dp = dst + (size_t)bc * 4096;
  for (int s = tid; s < 4096; s += 256) {
    int h = s >> 6, w = s & 63;
    tl[w][h] = sp[s];
  }
  __syncthreads();
  for (int s = tid; s < 4096; s += 256) dp[s] = tl[s >> 6][s & 63];
}

// ---------------- final 1x1 conv + relu + 8x8 upsample ----------------

__global__ void rf_final(const float* __restrict__ t, const float* __restrict__ ow,
                         const float* __restrict__ ob, float* __restrict__ out) {
  int b = blockIdx.y;
  int s = blockIdx.x * 256 + threadIdx.x;  // 0..4095
  int w = s >> 6, h = s & 63;
  float acc = ob[0];
  for (int c = 0; c < 64; ++c)
    acc += ow[c] * t[(((size_t)b * 64 + c) * 64 + w) * 64 + h];
  acc = fmaxf(acc, 0.f);
  float4 vv = make_float4(acc, acc, acc, acc);
  for (int dy = 0; dy < 8; ++dy) {
    float* dp = out + ((size_t)b * 512 + h * 8 + dy) * 512 + w * 8;
    *(float4*)dp = vv;
    *(float4*)(dp + 4) = vv;
  }
}

// ---------------- launch ----------------

extern "C" void kernel_launch(void* const* d_in, const int* in_sizes, int n_in,
                              void* d_out, int out_size, void* d_ws, size_t ws_size,
                              hipStream_t stream) {
  const float* in    = (const float*)d_in[0];
  const float* wA    = (const float*)d_in[1];
  const float* bA    = (const float*)d_in[2];
  const float* wB    = (const float*)d_in[3];
  const float* wC    = (const float*)d_in[5];
  const float* bC    = (const float*)d_in[6];
  const float* gamma = (const float*)d_in[7];
  const float* bw1 = (const float*)d_in[8];  const float* bb1 = (const float*)d_in[9];
  const float* bw2 = (const float*)d_in[10]; const float* bb2 = (const float*)d_in[11];
  const float* bw3 = (const float*)d_in[12]; const float* bb3 = (const float*)d_in[13];
  const float* bw4 = (const float*)d_in[14]; const float* bb4 = (const float*)d_in[15];
  const float* bw5 = (const float*)d_in[16]; const float* bb5 = (const float*)d_in[17];
  const float* bw6 = (const float*)d_in[18]; const float* bb6 = (const float*)d_in[19];
  const float* du_w = (const float*)d_in[20]; const float* du_b = (const float*)d_in[21];
  const float* lr_w = (const float*)d_in[22]; const float* lr_b = (const float*)d_in[23];
  const float* ow   = (const float*)d_in[24]; const float* ob   = (const float*)d_in[25];
  float* out = (float*)d_out;
  float* ws = (float*)d_ws;

  // region map (f32 slots)
  float* fv  = ws;                            // R0, phase 1-2
  f16* yH  = (f16*)(ws + 16777216);           // R1
  f16* yL  = (f16*)(ws + 25165824);
  f16* w1h = (f16*)(ws + 0);        f16* w1l = (f16*)(ws + 2359296);
  f16* c1H = (f16*)(ws + 4718592);  f16* c1L = (f16*)(ws + 8912896);
  f16* w3h = (f16*)(ws + 13107200); f16* w3l = (f16*)(ws + 14286848);
  f16* w2h = (f16*)(ws + 16777216); f16* w2l = (f16*)(ws + 17956864);
  f16* c2H = (f16*)(ws + 19136512); f16* c2L = (f16*)(ws + 23330816);
  f16* w4h = (f16*)(ws + 27525120); f16* w4l = (f16*)(ws + 28114944);
  f16* c4H = (f16*)(ws + 28704768); f16* c4L = (f16*)(ws + 30801920);
  f16* c3H = c1H;                   f16* c3L = c1L;
  f16* w5h = (f16*)(ws + 0);        f16* w5l = (f16*)(ws + 147456);
  f16* c5H = (f16*)(ws + 294912);   f16* c5L = (f16*)(ws + 1343488);
  f16* w6h = (f16*)(ws + 2392064);  f16* w6l = (f16*)(ws + 2428928);
  float* tin = ws + 4718592;
  float* t0  = ws + 5767168;
  float* t1  = ws + 6815744;
  float* sm = ws + 33554432;
  float* A_  = sm;
  float* M_  = sm + 16384;
  float* iZ  = sm + 32768;
  float* u_  = sm + 49152;
  float* s_  = sm + 50176;
  float* c0_ = sm + 50304;
  float* fst = sm + 50308;

  rf_s<<<1, 128, 0, stream>>>(wB, bA, s_, c0_);
  rf_u<<<4, 256, 0, stream>>>(wA, s_, u_);
  rf_fstat<<<4, 256, 0, stream>>>(in, fst);
  rf_A<<<dim3(16, 4), 256, 0, stream>>>(in, u_, c0_, fst, A_, M_);
  rf_Z<<<4096, 256, 0, stream>>>(in, A_, M_, iZ);
  rf_vgemm<<<dim3(16, 16, 4), 256, 0, stream>>>(in, wC, bC, fv);
  rf_att<<<dim3(16, 16, 4), 256, 0, stream>>>(in, fv, A_, M_, iZ, gamma, yH, yL);

  // fv dead -> prep w1, w3 in R0
  rf_wsplit<<<2048, 256, 0, stream>>>(bw1, w1h, w1l, 512, 1024);
  rf_wsplit<<<1024, 256, 0, stream>>>(bw3, w3h, w3l, 512, 512);
  rf_mconv<128, 128, false><<<dim3(128, 4), 256, 0, stream>>>(
      yH, yL, w1h, w1l, bb1, c1H, c1L, nullptr, 1024, 512);
  // y dead -> prep w2,w4 in R1; w1 dead -> w5,w6 in R0
  rf_wsplit<<<1024, 256, 0, stream>>>(bw2, w2h, w2l, 512, 512);
  rf_wsplit<<<512, 256, 0, stream>>>(bw4, w4h, w4l, 256, 512);
  rf_wsplit<<<128, 256, 0, stream>>>(bw5, w5h, w5l, 128, 256);
  rf_wsplit<<<32, 256, 0, stream>>>(bw6, w6h, w6l, 64, 128);
  rf_mconv<128, 128, false><<<dim3(128, 4), 256, 0, stream>>>(
      c1H, c1L, w2h, w2l, bb2, c2H, c2L, nullptr, 512, 512);
  rf_mconv<128, 128, false><<<dim3(128, 4), 256, 0, stream>>>(
      c2H, c2L, w3h, w3l, bb3, c3H, c3L, nullptr, 512, 512);
  rf_mconv<128, 128, false><<<dim3(128, 2), 256, 0, stream>>>(
      c3H, c3L, w4h, w4l, bb4, c4H, c4L, nullptr, 512, 256);
  rf_mconv<128, 128, false><<<dim3(128, 1), 256, 0, stream>>>(
      c4H, c4L, w5h, w5l, bb5, c5H, c5L, nullptr, 256, 128);
  rf_mconv<256, 64, true><<<dim3(64, 1), 256, 0, stream>>>(
      c5H, c5L, w6h, w6l, bb6, nullptr, nullptr, tin, 128, 64);

  rf_scan<<<4, 512, 0, stream>>>(tin, t0, du_w, du_b, +1);
  rf_scan<<<4, 512, 0, stream>>>(t0, t1, du_w, du_b, -1);
  rf_transpose<<<256, 256, 0, stream>>>(t1, t0);
  rf_scan<<<4, 512, 0, stream>>>(t0, t1, lr_w, lr_b, +1);
  rf_scan<<<4, 512, 0, stream>>>(t1, t0, lr_w, lr_b, -1);
  rf_final<<<dim3(16, 4), 256, 0, stream>>>(t0, ow, ob, out);
}

// Round 4
// 8187.823 us; speedup vs baseline: 1.8853x; 1.2592x over previous
//
#include <hip/hip_runtime.h>

// resFAN round 4: fixes round-3 workspace layout bug (f16 buffers were sized
// in f32 slots -> 2x overflow, xT/wC/v clobbered each other).  x now single
// fp16 (scale 16, no lo residual: error budget 1.6e-4 in v, damped by
// gamma=0.1 + conv chain to ~1e-6 at output).  wC keeps hi/lo split.
//
// ws layout (f32 slots), total 33,604,744:
//  phase1: vH [0,8388608) vL [8388608,16777216)
//          xT(single) [16777216,25165824)  wCh/wCl [25165824,26214400)
//          yH [16777216,25165824) yL [25165824,33554432)  (after xT/wC dead)
//  convs : identical to round 2 (passed): w1|c1|w3 low half, w2|c2|w4|c4 high
//  scans : w5|c5|w6|tin|t0|t1 low ; stats @33554432

#define NPIX 4096

typedef _Float16 f16;
typedef _Float16 f16x8 __attribute__((ext_vector_type(8)));
typedef _Float16 f16x4 __attribute__((ext_vector_type(4)));
typedef float f32x4 __attribute__((ext_vector_type(4)));

__device__ inline void async16(const void* g, void* l) {
  __builtin_amdgcn_global_load_lds(
      (const __attribute__((address_space(1))) unsigned int*)g,
      (__attribute__((address_space(3))) unsigned int*)l, 16, 0, 0);
}

// ---------------- small prep kernels ----------------

__global__ void rf_s(const float* __restrict__ wB, const float* __restrict__ bA,
                     float* __restrict__ s_out, float* __restrict__ c0_out) {
  int c = threadIdx.x;  // 128 threads
  const float* row = wB + (size_t)c * 1024;
  float acc = 0.f;
  for (int i = 0; i < 1024; ++i) acc += row[i];
  s_out[c] = acc;
  __shared__ float sh[128];
  sh[c] = acc * bA[c];
  __syncthreads();
  for (int off = 64; off > 0; off >>= 1) {
    if (c < off) sh[c] += sh[c + off];
    __syncthreads();
  }
  if (c == 0) c0_out[0] = sh[0];
}

__global__ void rf_u(const float* __restrict__ wA, const float* __restrict__ s,
                     float* __restrict__ u) {
  int i = blockIdx.x * 256 + threadIdx.x;  // 1024 total
  float acc = 0.f;
  for (int c = 0; c < 128; ++c) acc += s[c] * wA[(size_t)c * 1024 + i];
  u[i] = acc;
}

__global__ void rf_fstat(const float* __restrict__ in, float* __restrict__ fstat) {
  int b = blockIdx.x;
  int t = threadIdx.x;
  const float* f = in + ((size_t)b * 1025 + 1024) * NPIX;
  float mx = -1e30f, mn = 1e30f;
  for (int j = t; j < NPIX; j += 256) {
    float v = f[j];
    mx = fmaxf(mx, v);
    mn = fminf(mn, v);
  }
  __shared__ float smx[256], smn[256];
  smx[t] = mx; smn[t] = mn;
  __syncthreads();
  for (int off = 128; off > 0; off >>= 1) {
    if (t < off) {
      smx[t] = fmaxf(smx[t], smx[t + off]);
      smn[t] = fminf(smn[t], smn[t + off]);
    }
    __syncthreads();
  }
  if (t == 0) { fstat[b] = smx[0]; fstat[4 + b] = smn[0]; }
}

__global__ __launch_bounds__(256) void rf_A(const float* __restrict__ in,
                                            const float* __restrict__ u,
                                            const float* __restrict__ c0p,
                                            const float* __restrict__ fst,
                                            float* __restrict__ A, float* __restrict__ M) {
  __shared__ float ul[1024];
  int b = blockIdx.y;
  int n = blockIdx.x * 256 + threadIdx.x;
  for (int s = threadIdx.x; s < 1024; s += 256) ul[s] = u[s];
  __syncthreads();
  const float* xp = in + (size_t)b * 1025 * NPIX + n;
  float acc = c0p[0];
#pragma unroll 8
  for (int i = 0; i < 1024; ++i) acc = fmaf(ul[i], xp[(size_t)i * NPIX], acc);
  A[b * NPIX + n] = acc;
  M[b * NPIX + n] = fmaxf(acc * fst[b], acc * fst[4 + b]);
}

__global__ void rf_Z(const float* __restrict__ in, const float* __restrict__ A,
                     const float* __restrict__ M, float* __restrict__ iZ) {
  int idx = blockIdx.x * 4 + (threadIdx.x >> 6);  // (b,n) pair, 16384 total
  int lane = threadIdx.x & 63;
  int b = idx >> 12;
  const float* f = in + ((size_t)b * 1025 + 1024) * NPIX;
  float a = A[idx], m = M[idx];
  float acc = 0.f;
#pragma unroll 4
  for (int it = 0; it < 64; ++it) acc += __expf(a * f[lane + it * 64] - m);
  for (int off = 32; off > 0; off >>= 1) acc += __shfl_down(acc, off, 64);
  if (lane == 0) iZ[idx] = 1.0f / acc;
}

// ---------------- x transpose: [b][ci][n] f32 -> [b][n][ci] f16, scale 16 ---

__global__ void rf_xsplit(const float* __restrict__ in, f16* __restrict__ xh) {
  __shared__ float tl[64][65];
  int nt = blockIdx.x, ct = blockIdx.y, b = blockIdx.z;
  int n0 = nt * 64, c0 = ct * 64;
  int tid = threadIdx.x;
  for (int s = tid; s < 4096; s += 256) {
    int r = s >> 6, c = s & 63;
    tl[r][c] = in[((size_t)b * 1025 + c0 + r) * NPIX + n0 + c];
  }
  __syncthreads();
  for (int s = tid; s < 512; s += 256) {
    int n = s >> 3, g = s & 7;
    f16x8 hb;
#pragma unroll
    for (int q = 0; q < 8; ++q) hb[q] = (f16)(16.f * tl[g * 8 + q][n]);
    size_t o = ((size_t)b * NPIX + n0 + n) * 1024 + c0 + g * 8;
    *(f16x8*)&xh[o] = hb;
  }
}

// ---------------- wC split: [1024][1024] f32 -> f16 pair, scale 256 --------

__global__ void rf_wCsplit(const float* __restrict__ wC, f16* __restrict__ wh,
                           f16* __restrict__ wl) {
  int base = (blockIdx.x * 256 + threadIdx.x) * 8;
  f16x8 hb, lb;
#pragma unroll
  for (int q = 0; q < 8; ++q) {
    float v = 256.f * wC[base + q];
    f16 h = (f16)v;
    hb[q] = h; lb[q] = (f16)(v - (float)h);
  }
  *(f16x8*)&wh[base] = hb;
  *(f16x8*)&wl[base] = lb;
}

// ---------------- MFMA v-GEMM: v = wC @ x + bC -> split fp16 [b][c][j] -----
// M=128 c, N=128 j, K=1024 ci.  A = wC split (scale 256), B = xT (scale 16).

__global__ __launch_bounds__(256, 2) void rf_vgemmm(
    const f16* __restrict__ wh, const f16* __restrict__ wl,
    const f16* __restrict__ xh,
    const float* __restrict__ bC, f16* __restrict__ vH, f16* __restrict__ vL) {
  __shared__ f16 sAh[4096], sAl[4096], sBh[4096];
  const int tid = threadIdx.x;
  const int nb = blockIdx.x * 128, cb = blockIdx.y * 128, b = blockIdx.z;
  const int pA = tid & 127;
  const int wv = tid >> 6, lane = tid & 63;
  const int mrow = lane & 15, quad = lane >> 4;
  const int wm = (wv & 1) * 64, wn = (wv >> 1) * 64;
  const size_t abase = (size_t)(cb + pA) * 1024;
  const size_t bbase = ((size_t)b * NPIX + nb + pA) * 1024;
  f32x4 acc[4][4];
#pragma unroll
  for (int i = 0; i < 4; ++i)
#pragma unroll
    for (int j = 0; j < 4; ++j) acc[i][j] = (f32x4){0.f, 0.f, 0.f, 0.f};
  for (int k0 = 0; k0 < 1024; k0 += 32) {
#pragma unroll
    for (int s = 0; s < 2; ++s) {
      const int cc = ((tid + 256 * s) >> 7) & 3;
      const int lb = ((tid & ~63) + 256 * s) * 8;
      size_t ga = abase + k0 + cc * 8;
      size_t gb = bbase + k0 + cc * 8;
      async16(wh + ga, &sAh[lb]);
      async16(wl + ga, &sAl[lb]);
      async16(xh + gb, &sBh[lb]);
    }
    __syncthreads();
    f16x8 fah[4], fal[4], fbh[4];
#pragma unroll
    for (int mi = 0; mi < 4; ++mi) {
      int ix = (quad * 128 + wm + mi * 16 + mrow) * 8;
      fah[mi] = *(const f16x8*)&sAh[ix];
      fal[mi] = *(const f16x8*)&sAl[ix];
    }
#pragma unroll
    for (int ni = 0; ni < 4; ++ni) {
      int ix = (quad * 128 + wn + ni * 16 + mrow) * 8;
      fbh[ni] = *(const f16x8*)&sBh[ix];
    }
#pragma unroll
    for (int mi = 0; mi < 4; ++mi)
#pragma unroll
      for (int ni = 0; ni < 4; ++ni)
        acc[mi][ni] = __builtin_amdgcn_mfma_f32_16x16x32_f16(fah[mi], fbh[ni], acc[mi][ni], 0, 0, 0);
#pragma unroll
    for (int mi = 0; mi < 4; ++mi)
#pragma unroll
      for (int ni = 0; ni < 4; ++ni)
        acc[mi][ni] = __builtin_amdgcn_mfma_f32_16x16x32_f16(fal[mi], fbh[ni], acc[mi][ni], 0, 0, 0);
    __syncthreads();
  }
  const float inv = 1.0f / 4096.0f;
#pragma unroll
  for (int mi = 0; mi < 4; ++mi) {
#pragma unroll
    for (int rg = 0; rg < 4; ++rg) {
      int c = cb + wm + mi * 16 + quad * 4 + rg;
      float bv = bC[c];
#pragma unroll
      for (int ni = 0; ni < 4; ++ni) {
        int j = nb + wn + ni * 16 + mrow;
        float v = acc[mi][ni][rg] * inv + bv;
        float sv = 16.f * v;
        f16 h = (f16)sv;
        size_t o = ((size_t)b * 1024 + c) * NPIX + j;
        vH[o] = h;
        vL[o] = (f16)(sv - (float)h);
      }
    }
  }
}

// ---------------- MFMA attention out-GEMM + residual -> split y ------------
// out[c,i] = sum_j v[c,j]*p[i,j]; p = exp(A_i f_j - M_i)*iZ_i generated
// per 32-chunk in registers, split fp16 -> LDS B-frag layout.
// y = gamma*out + x, stored channels-last split fp16 (scale 16).

__global__ __launch_bounds__(256, 2) void rf_attm(
    const f16* __restrict__ vH, const f16* __restrict__ vL,
    const float* __restrict__ Aarr, const float* __restrict__ Marr,
    const float* __restrict__ iZ, const float* __restrict__ in,
    const float* __restrict__ gptr, f16* __restrict__ yH, f16* __restrict__ yL) {
  __shared__ f16 sAh[4096], sAl[4096], sPh[4096], sPl[4096];
  const int tid = threadIdx.x;
  const int ib = blockIdx.x * 128, cb = blockIdx.y * 128, b = blockIdx.z;
  const int pA = tid & 127;
  const int wv = tid >> 6, lane = tid & 63;
  const int mrow = lane & 15, quad = lane >> 4;
  const int wm = (wv & 1) * 64, wn = (wv >> 1) * 64;
  const size_t vbase = ((size_t)b * 1024 + cb + pA) * NPIX;
  const int ni_ = tid & 127;
  const int kc0 = tid >> 7;  // 0..1
  const float av = Aarr[b * NPIX + ib + ni_];
  const float mv = Marr[b * NPIX + ib + ni_];
  const float zv = iZ[b * NPIX + ib + ni_] * 16.f;
  const float* f = in + ((size_t)b * 1025 + 1024) * NPIX;
  f32x4 acc[4][4];
#pragma unroll
  for (int i = 0; i < 4; ++i)
#pragma unroll
    for (int j = 0; j < 4; ++j) acc[i][j] = (f32x4){0.f, 0.f, 0.f, 0.f};
  for (int j0 = 0; j0 < NPIX; j0 += 32) {
#pragma unroll
    for (int s = 0; s < 2; ++s) {
      const int cc = ((tid + 256 * s) >> 7) & 3;
      const int lb = ((tid & ~63) + 256 * s) * 8;
      size_t ga = vbase + j0 + cc * 8;
      async16(vH + ga, &sAh[lb]);
      async16(vL + ga, &sAl[lb]);
    }
#pragma unroll
    for (int it = 0; it < 2; ++it) {
      const int kc = kc0 + 2 * it;
      const float4 fa = *(const float4*)&f[j0 + kc * 8];
      const float4 fb = *(const float4*)&f[j0 + kc * 8 + 4];
      const float fj[8] = {fa.x, fa.y, fa.z, fa.w, fb.x, fb.y, fb.z, fb.w};
      f16x8 ph, plo;
#pragma unroll
      for (int q = 0; q < 8; ++q) {
        float p = __expf(fmaf(av, fj[q], -mv)) * zv;
        f16 h = (f16)p;
        ph[q] = h;
        plo[q] = (f16)(p - (float)h);
      }
      const int off = (kc * 128 + ni_) * 8;
      *(f16x8*)&sPh[off] = ph;
      *(f16x8*)&sPl[off] = plo;
    }
    __syncthreads();
    f16x8 fah[4], fal[4], fbh[4], fbl[4];
#pragma unroll
    for (int mi = 0; mi < 4; ++mi) {
      int ix = (quad * 128 + wm + mi * 16 + mrow) * 8;
      fah[mi] = *(const f16x8*)&sAh[ix];
      fal[mi] = *(const f16x8*)&sAl[ix];
    }
#pragma unroll
    for (int ni = 0; ni < 4; ++ni) {
      int ix = (quad * 128 + wn + ni * 16 + mrow) * 8;
      fbh[ni] = *(const f16x8*)&sPh[ix];
      fbl[ni] = *(const f16x8*)&sPl[ix];
    }
#pragma unroll
    for (int mi = 0; mi < 4; ++mi)
#pragma unroll
      for (int ni = 0; ni < 4; ++ni)
        acc[mi][ni] = __builtin_amdgcn_mfma_f32_16x16x32_f16(fah[mi], fbh[ni], acc[mi][ni], 0, 0, 0);
#pragma unroll
    for (int mi = 0; mi < 4; ++mi)
#pragma unroll
      for (int ni = 0; ni < 4; ++ni)
        acc[mi][ni] = __builtin_amdgcn_mfma_f32_16x16x32_f16(fah[mi], fbl[ni], acc[mi][ni], 0, 0, 0);
#pragma unroll
    for (int mi = 0; mi < 4; ++mi)
#pragma unroll
      for (int ni = 0; ni < 4; ++ni)
        acc[mi][ni] = __builtin_amdgcn_mfma_f32_16x16x32_f16(fal[mi], fbh[ni], acc[mi][ni], 0, 0, 0);
    __syncthreads();
  }
  const float g = gptr[0];
  const float inv = 1.0f / 256.0f;
#pragma unroll
  for (int mi = 0; mi < 4; ++mi) {
    const int cbase = cb + wm + mi * 16 + quad * 4;
#pragma unroll
    for (int ni = 0; ni < 4; ++ni) {
      const int i = ib + wn + ni * 16 + mrow;
      f16x4 hv, lv;
#pragma unroll
      for (int rg = 0; rg < 4; ++rg) {
        float xr = in[((size_t)b * 1025 + cbase + rg) * NPIX + i];
        float sv = 16.f * (g * (acc[mi][ni][rg] * inv) + xr);
        f16 h = (f16)sv;
        hv[rg] = h;
        lv[rg] = (f16)(sv - (float)h);
      }
      size_t o = ((size_t)b * NPIX + i) * 1024 + cbase;
      *(f16x4*)&yH[o] = hv;
      *(f16x4*)&yL[o] = lv;
    }
  }
}

// ---------------- weight split prep: [CO][CI][3][3] -> [9][CO][CI] hi/lo ----

__global__ void rf_wsplit(const float* __restrict__ w, f16* __restrict__ wh,
                          f16* __restrict__ wlo, int CO, int CI) {
  int idx = blockIdx.x * 256 + threadIdx.x;  // co*CI + ci
  if (idx >= CO * CI) return;
  int co = idx / CI, ci = idx - co * CI;
#pragma unroll
  for (int t = 0; t < 9; ++t) {
    float v = 256.0f * w[(size_t)idx * 9 + t];
    f16 h = (f16)v;
    size_t o = ((size_t)t * CO + co) * CI + ci;
    wh[o] = h;
    wlo[o] = (f16)(v - (float)h);
  }
}

// ---------------- MFMA dilated 3x3 conv (implicit GEMM, split fp16) --------

template <int BM, int BN, bool F32OUT>
__global__ __launch_bounds__(256, 2) void rf_mconv(
    const f16* __restrict__ xh, const f16* __restrict__ xl,
    const f16* __restrict__ wh, const f16* __restrict__ wlo,
    const float* __restrict__ bias,
    f16* __restrict__ oh, f16* __restrict__ ol, float* __restrict__ of,
    int CI, int CO) {
  constexpr int ROWS = BM / 64;
  constexpr int TPI = 4096 / BM;
  constexpr int NSA = BM / 64;
  constexpr int NSB = BN / 64;
  __shared__ f16 sAh[BM * 32], sAl[BM * 32], sBh[BN * 32], sBl[BN * 32];
  const int tid = threadIdx.x;
  const int blkpx = blockIdx.x;
  const int cob = blockIdx.y * BN;
  const int b = blkpx / TPI;
  const int h0 = (blkpx - b * TPI) * ROWS;

  const int pA = tid & (BM - 1);
  const int rA = pA >> 6, wpx = pA & 63;
  const int pB = tid & (BN - 1);

  const int wv = tid >> 6, lane = tid & 63;
  const int mrow = lane & 15, quad = lane >> 4;
  const int wm = (BN == 128) ? (wv & 1) * 64 : wv * 64;
  const int wn = (BN == 128) ? (wv >> 1) * 64 : 0;

  f32x4 acc[4][4];
#pragma unroll
  for (int i = 0; i < 4; ++i)
#pragma unroll
    for (int j = 0; j < 4; ++j) acc[i][j] = (f32x4){0.f, 0.f, 0.f, 0.f};

  const int KI = CI >> 5;
  for (int t = 0; t < 9; ++t) {
    const int dh = (t / 3) * 2 - 2, dw = (t - (t / 3) * 3) * 2 - 2;
    const int hin = h0 + rA + dh, win = wpx + dw;
    const bool val = ((unsigned)hin < 64u) && ((unsigned)win < 64u);
    const size_t apix = (((size_t)b * 64 + (val ? hin : 0)) * 64 + (val ? win : 0)) * CI;
#pragma unroll
    for (int s = 0; s < NSA; ++s) {
      int c = tid + 256 * s;
      *(int4*)&sAh[c * 8] = make_int4(0, 0, 0, 0);
      *(int4*)&sAl[c * 8] = make_int4(0, 0, 0, 0);
    }
    __syncthreads();
    const size_t wbase = ((size_t)t * CO + cob + pB) * CI;
    for (int k = 0; k < KI; ++k) {
      const int ci0 = k << 5;
#pragma unroll
      for (int s = 0; s < NSA; ++s) {
        const int cc = ((tid + 256 * s) / BM) & 3;
        const int lb = ((tid & ~63) + 256 * s) * 8;
        if (val) {
          size_t go = apix + ci0 + cc * 8;
          async16(xh + go, &sAh[lb]);
          async16(xl + go, &sAl[lb]);
        }
      }
#pragma unroll
      for (int s = 0; s < NSB; ++s) {
        const int cc = ((tid + 256 * s) / BN) & 3;
        const int lb = ((tid & ~63) + 256 * s) * 8;
        size_t go = wbase + ci0 + cc * 8;
        async16(wh + go, &sBh[lb]);
        async16(wlo + go, &sBl[lb]);
      }
      __syncthreads();
      f16x8 fah[4], fal[4], fbh[4], fbl[4];
#pragma unroll
      for (int mi = 0; mi < 4; ++mi) {
        int ix = (quad * BM + wm + mi * 16 + mrow) * 8;
        fah[mi] = *(const f16x8*)&sAh[ix];
        fal[mi] = *(const f16x8*)&sAl[ix];
      }
#pragma unroll
      for (int ni = 0; ni < 4; ++ni) {
        int ix = (quad * BN + wn + ni * 16 + mrow) * 8;
        fbh[ni] = *(const f16x8*)&sBh[ix];
        fbl[ni] = *(const f16x8*)&sBl[ix];
      }
#pragma unroll
      for (int mi = 0; mi < 4; ++mi)
#pragma unroll
        for (int ni = 0; ni < 4; ++ni)
          acc[mi][ni] = __builtin_amdgcn_mfma_f32_16x16x32_f16(fah[mi], fbh[ni], acc[mi][ni], 0, 0, 0);
#pragma unroll
      for (int mi = 0; mi < 4; ++mi)
#pragma unroll
        for (int ni = 0; ni < 4; ++ni)
          acc[mi][ni] = __builtin_amdgcn_mfma_f32_16x16x32_f16(fah[mi], fbl[ni], acc[mi][ni], 0, 0, 0);
#pragma unroll
      for (int mi = 0; mi < 4; ++mi)
#pragma unroll
        for (int ni = 0; ni < 4; ++ni)
          acc[mi][ni] = __builtin_amdgcn_mfma_f32_16x16x32_f16(fal[mi], fbh[ni], acc[mi][ni], 0, 0, 0);
      __syncthreads();
    }
  }
  const float inv = 1.0f / 4096.0f;
  float bvs[4];
#pragma unroll
  for (int ni = 0; ni < 4; ++ni) bvs[ni] = bias[cob + wn + ni * 16 + mrow];
#pragma unroll
  for (int mi = 0; mi < 4; ++mi) {
#pragma unroll
    for (int rg = 0; rg < 4; ++rg) {
      int px = wm + mi * 16 + quad * 4 + rg;
      int hh = h0 + (px >> 6), wwp = px & 63;
#pragma unroll
      for (int ni = 0; ni < 4; ++ni) {
        int co = cob + wn + ni * 16 + mrow;
        float vv = fmaxf(acc[mi][ni][rg] * inv + bvs[ni], 0.f);
        if (F32OUT) {
          of[(((size_t)b * CO + co) * 64 + hh) * 64 + wwp] = vv;
        } else {
          float sv = vv * 16.f;
          f16 hv = (f16)sv;
          size_t o = (((size_t)b * 64 + hh) * 64 + wwp) * CO + co;
          oh[o] = hv;
          ol[o] = (f16)(sv - (float)hv);
        }
      }
    }
  }
}

// ---------------- recurrent scan pass (conv1d k=9 pad 4 over 'pos') --------

__global__ __launch_bounds__(512) void rf_scan(const float* __restrict__ src,
                                               float* __restrict__ dst,
                                               const float* __restrict__ wconv,
                                               const float* __restrict__ bias,
                                               int dir) {
  int b = blockIdx.x;
  __shared__ float carry[64][74];
  int tid = threadIdx.x;
  int co = tid >> 3;
  int cig = tid & 7;
  float wreg[72];
#pragma unroll
  for (int cl = 0; cl < 8; ++cl)
#pragma unroll
    for (int k = 0; k < 9; ++k)
      wreg[cl * 9 + k] = wconv[((size_t)co * 64 + cig * 8 + cl) * 9 + k];
  float bv = bias[co];
  for (int s = tid; s < 64 * 74; s += 512) {
    int ci = s / 74;
    int p = s - ci * 74;
    if (p < 4 || p >= 68) carry[ci][p] = 0.f;
  }
  {
    int step = (dir > 0) ? 0 : 63;
    const float* sp = src + (((size_t)b * 64 + co) * 64 + step) * 64;
    float* dp = dst + (((size_t)b * 64 + co) * 64 + step) * 64;
#pragma unroll
    for (int m = 0; m < 8; ++m) {
      int pos = cig * 8 + m;
      float v = sp[pos];
      dp[pos] = v;
      carry[co][4 + pos] = v;
    }
  }
  __syncthreads();
  float val0[4], val1[4];
  for (int s = 1; s < 64; ++s) {
    int step = (dir > 0) ? s : 63 - s;
    const float* sp = src + (((size_t)b * 64 + co) * 64 + step) * 64;
    float* dp = dst + (((size_t)b * 64 + co) * 64 + step) * 64;
#pragma unroll
    for (int half = 0; half < 2; ++half) {
      float accv[32];
#pragma unroll
      for (int p = 0; p < 32; ++p) accv[p] = 0.f;
#pragma unroll
      for (int cl = 0; cl < 8; ++cl) {
        int ci = cig * 8 + cl;
        float xr[40];
#pragma unroll
        for (int m = 0; m < 20; ++m) {
          float2 t2 = *(const float2*)&carry[ci][half * 32 + 2 * m];
          xr[2 * m] = t2.x; xr[2 * m + 1] = t2.y;
        }
#pragma unroll
        for (int k = 0; k < 9; ++k) {
          float wv = wreg[cl * 9 + k];
#pragma unroll
          for (int p = 0; p < 32; ++p) accv[p] = fmaf(wv, xr[p + k], accv[p]);
        }
      }
#pragma unroll
      for (int m = 1; m < 8; m <<= 1)
#pragma unroll
        for (int p = 0; p < 32; ++p) accv[p] += __shfl_xor(accv[p], m, 64);
      float* vout = half ? val1 : val0;
#pragma unroll
      for (int q = 0; q < 4; ++q) {
        int pos = half * 32 + cig * 4 + q;
        vout[q] = fmaxf(accv[cig * 4 + q] + bv, 0.f) + sp[pos];
      }
    }
    __syncthreads();
#pragma unroll
    for (int q = 0; q < 4; ++q) {
      int p0 = cig * 4 + q;
      int p1 = 32 + cig * 4 + q;
      carry[co][4 + p0] = val0[q]; dp[p0] = val0[q];
      carry[co][4 + p1] = val1[q]; dp[p1] = val1[q];
    }
    __syncthreads();
  }
}

// ---------------- transpose last two dims (64x64) per (b,c) ----------------

__global__ void rf_transpose(const float* __restrict__ src, float* __restrict__ dst) {
  int bc = blockIdx.x;  // 256
  __shared__ float tl[64][65];
  int tid = threadIdx.x;
  const float* sp = src + (size_t)bc * 4096;
  float* dp = dst + (size_t)bc * 4096;
  for (int s = tid; s < 4096; s += 256) {
    int h = s >> 6, w = s & 63;
    tl[w][h] = sp[s];
  }
  __syncthreads();
  for (int s = tid; s < 4096; s += 256) dp[s] = tl[s >> 6][s & 63];
}

// ---------------- final 1x1 conv + relu + 8x8 upsample ----------------

__global__ void rf_final(const float* __restrict__ t, const float* __restrict__ ow,
                         const float* __restrict__ ob, float* __restrict__ out) {
  int b = blockIdx.y;
  int s = blockIdx.x * 256 + threadIdx.x;  // 0..4095
  int w = s >> 6, h = s & 63;
  float acc = ob[0];
  for (int c = 0; c < 64; ++c)
    acc += ow[c] * t[(((size_t)b * 64 + c) * 64 + w) * 64 + h];
  acc = fmaxf(acc, 0.f);
  float4 vv = make_float4(acc, acc, acc, acc);
  for (int dy = 0; dy < 8; ++dy) {
    float* dp = out + ((size_t)b * 512 + h * 8 + dy) * 512 + w * 8;
    *(float4*)dp = vv;
    *(float4*)(dp + 4) = vv;
  }
}

// ---------------- launch ----------------

extern "C" void kernel_launch(void* const* d_in, const int* in_sizes, int n_in,
                              void* d_out, int out_size, void* d_ws, size_t ws_size,
                              hipStream_t stream) {
  const float* in    = (const float*)d_in[0];
  const float* wA    = (const float*)d_in[1];
  const float* bA    = (const float*)d_in[2];
  const float* wB    = (const float*)d_in[3];
  const float* wC    = (const float*)d_in[5];
  const float* bC    = (const float*)d_in[6];
  const float* gamma = (const float*)d_in[7];
  const float* bw1 = (const float*)d_in[8];  const float* bb1 = (const float*)d_in[9];
  const float* bw2 = (const float*)d_in[10]; const float* bb2 = (const float*)d_in[11];
  const float* bw3 = (const float*)d_in[12]; const float* bb3 = (const float*)d_in[13];
  const float* bw4 = (const float*)d_in[14]; const float* bb4 = (const float*)d_in[15];
  const float* bw5 = (const float*)d_in[16]; const float* bb5 = (const float*)d_in[17];
  const float* bw6 = (const float*)d_in[18]; const float* bb6 = (const float*)d_in[19];
  const float* du_w = (const float*)d_in[20]; const float* du_b = (const float*)d_in[21];
  const float* lr_w = (const float*)d_in[22]; const float* lr_b = (const float*)d_in[23];
  const float* ow   = (const float*)d_in[24]; const float* ob   = (const float*)d_in[25];
  float* out = (float*)d_out;
  float* ws = (float*)d_ws;

  // phase-1 buffers (sizes in f32 slots; f16 buffers need elems/2 slots)
  f16* vH  = (f16*)(ws + 0);         // 16,777,216 f16 = 8,388,608 slots
  f16* vL  = (f16*)(ws + 8388608);
  f16* xTh = (f16*)(ws + 16777216);  // 16,777,216 f16 (reuses y region, dead pre-attm)
  f16* wCh = (f16*)(ws + 25165824);  // 1,048,576 f16 = 524,288 slots
  f16* wCl = (f16*)(ws + 25690112);
  f16* yH  = (f16*)(ws + 16777216);  // written by attm after xT/wC dead
  f16* yL  = (f16*)(ws + 25165824);
  // conv phase (identical to round 2)
  f16* w1h = (f16*)(ws + 0);        f16* w1l = (f16*)(ws + 2359296);
  f16* c1H = (f16*)(ws + 4718592);  f16* c1L = (f16*)(ws + 8912896);
  f16* w3h = (f16*)(ws + 13107200); f16* w3l = (f16*)(ws + 14286848);
  f16* w2h = (f16*)(ws + 16777216); f16* w2l = (f16*)(ws + 17956864);
  f16* c2H = (f16*)(ws + 19136512); f16* c2L = (f16*)(ws + 23330816);
  f16* w4h = (f16*)(ws + 27525120); f16* w4l = (f16*)(ws + 28114944);
  f16* c4H = (f16*)(ws + 28704768); f16* c4L = (f16*)(ws + 30801920);
  f16* c3H = c1H;                   f16* c3L = c1L;
  f16* w5h = (f16*)(ws + 0);        f16* w5l = (f16*)(ws + 147456);
  f16* c5H = (f16*)(ws + 294912);   f16* c5L = (f16*)(ws + 1343488);
  f16* w6h = (f16*)(ws + 2392064);  f16* w6l = (f16*)(ws + 2428928);
  float* tin = ws + 4718592;
  float* t0  = ws + 5767168;
  float* t1  = ws + 6815744;
  float* sm = ws + 33554432;
  float* A_  = sm;
  float* M_  = sm + 16384;
  float* iZ  = sm + 32768;
  float* u_  = sm + 49152;
  float* s_  = sm + 50176;
  float* c0_ = sm + 50304;
  float* fst = sm + 50308;

  rf_s<<<1, 128, 0, stream>>>(wB, bA, s_, c0_);
  rf_u<<<4, 256, 0, stream>>>(wA, s_, u_);
  rf_fstat<<<4, 256, 0, stream>>>(in, fst);
  rf_A<<<dim3(16, 4), 256, 0, stream>>>(in, u_, c0_, fst, A_, M_);
  rf_Z<<<4096, 256, 0, stream>>>(in, A_, M_, iZ);
  rf_xsplit<<<dim3(64, 16, 4), 256, 0, stream>>>(in, xTh);
  rf_wCsplit<<<512, 256, 0, stream>>>(wC, wCh, wCl);
  rf_vgemmm<<<dim3(32, 8, 4), 256, 0, stream>>>(wCh, wCl, xTh, bC, vH, vL);
  rf_attm<<<dim3(32, 8, 4), 256, 0, stream>>>(vH, vL, A_, M_, iZ, in, gamma, yH, yL);

  // v dead after attm? no - attm reads v, writes y (disjoint). convs then reuse v region.
  rf_wsplit<<<2048, 256, 0, stream>>>(bw1, w1h, w1l, 512, 1024);
  rf_wsplit<<<1024, 256, 0, stream>>>(bw3, w3h, w3l, 512, 512);
  rf_mconv<128, 128, false><<<dim3(128, 4), 256, 0, stream>>>(
      yH, yL, w1h, w1l, bb1, c1H, c1L, nullptr, 1024, 512);
  // y dead -> prep w2,w4; w1 dead -> w5,w6
  rf_wsplit<<<1024, 256, 0, stream>>>(bw2, w2h, w2l, 512, 512);
  rf_wsplit<<<512, 256, 0, stream>>>(bw4, w4h, w4l, 256, 512);
  rf_wsplit<<<128, 256, 0, stream>>>(bw5, w5h, w5l, 128, 256);
  rf_wsplit<<<32, 256, 0, stream>>>(bw6, w6h, w6l, 64, 128);
  rf_mconv<128, 128, false><<<dim3(128, 4), 256, 0, stream>>>(
      c1H, c1L, w2h, w2l, bb2, c2H, c2L, nullptr, 512, 512);
  rf_mconv<128, 128, false><<<dim3(128, 4), 256, 0, stream>>>(
      c2H, c2L, w3h, w3l, bb3, c3H, c3L, nullptr, 512, 512);
  rf_mconv<128, 128, false><<<dim3(128, 2), 256, 0, stream>>>(
      c3H, c3L, w4h, w4l, bb4, c4H, c4L, nullptr, 512, 256);
  rf_mconv<128, 128, false><<<dim3(128, 1), 256, 0, stream>>>(
      c4H, c4L, w5h, w5l, bb5, c5H, c5L, nullptr, 256, 128);
  rf_mconv<256, 64, true><<<dim3(64, 1), 256, 0, stream>>>(
      c5H, c5L, w6h, w6l, bb6, nullptr, nullptr, tin, 128, 64);

  rf_scan<<<4, 512, 0, stream>>>(tin, t0, du_w, du_b, +1);
  rf_scan<<<4, 512, 0, stream>>>(t0, t1, du_w, du_b, -1);
  rf_transpose<<<256, 256, 0, stream>>>(t1, t0);
  rf_scan<<<4, 512, 0, stream>>>(t0, t1, lr_w, lr_b, +1);
  rf_scan<<<4, 512, 0, stream>>>(t1, t0, lr_w, lr_b, -1);
  rf_final<<<dim3(16, 4), 256, 0, stream>>>(t0, ow, ob, out);
}

// Round 5
// 3592.723 us; speedup vs baseline: 4.2967x; 2.2790x over previous
//
#include <hip/hip_runtime.h>

// resFAN round 5: recurrent scans moved to MFMA (split-fp16 x3, per-step
// 64x64xK576 GEMM on 1 CU/batch).  Carry in LDS [pos+4][ci] hi/lo fp16 with
// XOR-granule swizzle (conflict-free row-stride reads).  Weights pre-split
// into fragment order by rf_wfrag.  Everything else = round 4 (passed).

#define NPIX 4096

typedef _Float16 f16;
typedef _Float16 f16x8 __attribute__((ext_vector_type(8)));
typedef _Float16 f16x4 __attribute__((ext_vector_type(4)));
typedef float f32x4 __attribute__((ext_vector_type(4)));

__device__ inline void async16(const void* g, void* l) {
  __builtin_amdgcn_global_load_lds(
      (const __attribute__((address_space(1))) unsigned int*)g,
      (__attribute__((address_space(3))) unsigned int*)l, 16, 0, 0);
}

// ---------------- small prep kernels ----------------

__global__ void rf_s(const float* __restrict__ wB, const float* __restrict__ bA,
                     float* __restrict__ s_out, float* __restrict__ c0_out) {
  int c = threadIdx.x;  // 128 threads
  const float* row = wB + (size_t)c * 1024;
  float acc = 0.f;
  for (int i = 0; i < 1024; ++i) acc += row[i];
  s_out[c] = acc;
  __shared__ float sh[128];
  sh[c] = acc * bA[c];
  __syncthreads();
  for (int off = 64; off > 0; off >>= 1) {
    if (c < off) sh[c] += sh[c + off];
    __syncthreads();
  }
  if (c == 0) c0_out[0] = sh[0];
}

__global__ void rf_u(const float* __restrict__ wA, const float* __restrict__ s,
                     float* __restrict__ u) {
  int i = blockIdx.x * 256 + threadIdx.x;  // 1024 total
  float acc = 0.f;
  for (int c = 0; c < 128; ++c) acc += s[c] * wA[(size_t)c * 1024 + i];
  u[i] = acc;
}

__global__ void rf_fstat(const float* __restrict__ in, float* __restrict__ fstat) {
  int b = blockIdx.x;
  int t = threadIdx.x;
  const float* f = in + ((size_t)b * 1025 + 1024) * NPIX;
  float mx = -1e30f, mn = 1e30f;
  for (int j = t; j < NPIX; j += 256) {
    float v = f[j];
    mx = fmaxf(mx, v);
    mn = fminf(mn, v);
  }
  __shared__ float smx[256], smn[256];
  smx[t] = mx; smn[t] = mn;
  __syncthreads();
  for (int off = 128; off > 0; off >>= 1) {
    if (t < off) {
      smx[t] = fmaxf(smx[t], smx[t + off]);
      smn[t] = fminf(smn[t], smn[t + off]);
    }
    __syncthreads();
  }
  if (t == 0) { fstat[b] = smx[0]; fstat[4 + b] = smn[0]; }
}

__global__ __launch_bounds__(256) void rf_A(const float* __restrict__ in,
                                            const float* __restrict__ u,
                                            const float* __restrict__ c0p,
                                            const float* __restrict__ fst,
                                            float* __restrict__ A, float* __restrict__ M) {
  __shared__ float ul[1024];
  int b = blockIdx.y;
  int n = blockIdx.x * 256 + threadIdx.x;
  for (int s = threadIdx.x; s < 1024; s += 256) ul[s] = u[s];
  __syncthreads();
  const float* xp = in + (size_t)b * 1025 * NPIX + n;
  float acc = c0p[0];
#pragma unroll 8
  for (int i = 0; i < 1024; ++i) acc = fmaf(ul[i], xp[(size_t)i * NPIX], acc);
  A[b * NPIX + n] = acc;
  M[b * NPIX + n] = fmaxf(acc * fst[b], acc * fst[4 + b]);
}

__global__ void rf_Z(const float* __restrict__ in, const float* __restrict__ A,
                     const float* __restrict__ M, float* __restrict__ iZ) {
  int idx = blockIdx.x * 4 + (threadIdx.x >> 6);  // (b,n) pair, 16384 total
  int lane = threadIdx.x & 63;
  int b = idx >> 12;
  const float* f = in + ((size_t)b * 1025 + 1024) * NPIX;
  float a = A[idx], m = M[idx];
  float acc = 0.f;
#pragma unroll 4
  for (int it = 0; it < 64; ++it) acc += __expf(a * f[lane + it * 64] - m);
  for (int off = 32; off > 0; off >>= 1) acc += __shfl_down(acc, off, 64);
  if (lane == 0) iZ[idx] = 1.0f / acc;
}

// ---------------- x transpose: [b][ci][n] f32 -> [b][n][ci] f16, scale 16 ---

__global__ void rf_xsplit(const float* __restrict__ in, f16* __restrict__ xh) {
  __shared__ float tl[64][65];
  int nt = blockIdx.x, ct = blockIdx.y, b = blockIdx.z;
  int n0 = nt * 64, c0 = ct * 64;
  int tid = threadIdx.x;
  for (int s = tid; s < 4096; s += 256) {
    int r = s >> 6, c = s & 63;
    tl[r][c] = in[((size_t)b * 1025 + c0 + r) * NPIX + n0 + c];
  }
  __syncthreads();
  for (int s = tid; s < 512; s += 256) {
    int n = s >> 3, g = s & 7;
    f16x8 hb;
#pragma unroll
    for (int q = 0; q < 8; ++q) hb[q] = (f16)(16.f * tl[g * 8 + q][n]);
    size_t o = ((size_t)b * NPIX + n0 + n) * 1024 + c0 + g * 8;
    *(f16x8*)&xh[o] = hb;
  }
}

// ---------------- wC split: [1024][1024] f32 -> f16 pair, scale 256 --------

__global__ void rf_wCsplit(const float* __restrict__ wC, f16* __restrict__ wh,
                           f16* __restrict__ wl) {
  int base = (blockIdx.x * 256 + threadIdx.x) * 8;
  f16x8 hb, lb;
#pragma unroll
  for (int q = 0; q < 8; ++q) {
    float v = 256.f * wC[base + q];
    f16 h = (f16)v;
    hb[q] = h; lb[q] = (f16)(v - (float)h);
  }
  *(f16x8*)&wh[base] = hb;
  *(f16x8*)&wl[base] = lb;
}

// ---------------- MFMA v-GEMM: v = wC @ x + bC -> split fp16 [b][c][j] -----

__global__ __launch_bounds__(256, 2) void rf_vgemmm(
    const f16* __restrict__ wh, const f16* __restrict__ wl,
    const f16* __restrict__ xh,
    const float* __restrict__ bC, f16* __restrict__ vH, f16* __restrict__ vL) {
  __shared__ f16 sAh[4096], sAl[4096], sBh[4096];
  const int tid = threadIdx.x;
  const int nb = blockIdx.x * 128, cb = blockIdx.y * 128, b = blockIdx.z;
  const int pA = tid & 127;
  const int wv = tid >> 6, lane = tid & 63;
  const int mrow = lane & 15, quad = lane >> 4;
  const int wm = (wv & 1) * 64, wn = (wv >> 1) * 64;
  const size_t abase = (size_t)(cb + pA) * 1024;
  const size_t bbase = ((size_t)b * NPIX + nb + pA) * 1024;
  f32x4 acc[4][4];
#pragma unroll
  for (int i = 0; i < 4; ++i)
#pragma unroll
    for (int j = 0; j < 4; ++j) acc[i][j] = (f32x4){0.f, 0.f, 0.f, 0.f};
  for (int k0 = 0; k0 < 1024; k0 += 32) {
#pragma unroll
    for (int s = 0; s < 2; ++s) {
      const int cc = ((tid + 256 * s) >> 7) & 3;
      const int lb = ((tid & ~63) + 256 * s) * 8;
      size_t ga = abase + k0 + cc * 8;
      size_t gb = bbase + k0 + cc * 8;
      async16(wh + ga, &sAh[lb]);
      async16(wl + ga, &sAl[lb]);
      async16(xh + gb, &sBh[lb]);
    }
    __syncthreads();
    f16x8 fah[4], fal[4], fbh[4];
#pragma unroll
    for (int mi = 0; mi < 4; ++mi) {
      int ix = (quad * 128 + wm + mi * 16 + mrow) * 8;
      fah[mi] = *(const f16x8*)&sAh[ix];
      fal[mi] = *(const f16x8*)&sAl[ix];
    }
#pragma unroll
    for (int ni = 0; ni < 4; ++ni) {
      int ix = (quad * 128 + wn + ni * 16 + mrow) * 8;
      fbh[ni] = *(const f16x8*)&sBh[ix];
    }
#pragma unroll
    for (int mi = 0; mi < 4; ++mi)
#pragma unroll
      for (int ni = 0; ni < 4; ++ni)
        acc[mi][ni] = __builtin_amdgcn_mfma_f32_16x16x32_f16(fah[mi], fbh[ni], acc[mi][ni], 0, 0, 0);
#pragma unroll
    for (int mi = 0; mi < 4; ++mi)
#pragma unroll
      for (int ni = 0; ni < 4; ++ni)
        acc[mi][ni] = __builtin_amdgcn_mfma_f32_16x16x32_f16(fal[mi], fbh[ni], acc[mi][ni], 0, 0, 0);
    __syncthreads();
  }
  const float inv = 1.0f / 4096.0f;
#pragma unroll
  for (int mi = 0; mi < 4; ++mi) {
#pragma unroll
    for (int rg = 0; rg < 4; ++rg) {
      int c = cb + wm + mi * 16 + quad * 4 + rg;
      float bv = bC[c];
#pragma unroll
      for (int ni = 0; ni < 4; ++ni) {
        int j = nb + wn + ni * 16 + mrow;
        float v = acc[mi][ni][rg] * inv + bv;
        float sv = 16.f * v;
        f16 h = (f16)sv;
        size_t o = ((size_t)b * 1024 + c) * NPIX + j;
        vH[o] = h;
        vL[o] = (f16)(sv - (float)h);
      }
    }
  }
}

// ---------------- MFMA attention out-GEMM + residual -> split y ------------

__global__ __launch_bounds__(256, 2) void rf_attm(
    const f16* __restrict__ vH, const f16* __restrict__ vL,
    const float* __restrict__ Aarr, const float* __restrict__ Marr,
    const float* __restrict__ iZ, const float* __restrict__ in,
    const float* __restrict__ gptr, f16* __restrict__ yH, f16* __restrict__ yL) {
  __shared__ f16 sAh[4096], sAl[4096], sPh[4096], sPl[4096];
  const int tid = threadIdx.x;
  const int ib = blockIdx.x * 128, cb = blockIdx.y * 128, b = blockIdx.z;
  const int pA = tid & 127;
  const int wv = tid >> 6, lane = tid & 63;
  const int mrow = lane & 15, quad = lane >> 4;
  const int wm = (wv & 1) * 64, wn = (wv >> 1) * 64;
  const size_t vbase = ((size_t)b * 1024 + cb + pA) * NPIX;
  const int ni_ = tid & 127;
  const int kc0 = tid >> 7;  // 0..1
  const float av = Aarr[b * NPIX + ib + ni_];
  const float mv = Marr[b * NPIX + ib + ni_];
  const float zv = iZ[b * NPIX + ib + ni_] * 16.f;
  const float* f = in + ((size_t)b * 1025 + 1024) * NPIX;
  f32x4 acc[4][4];
#pragma unroll
  for (int i = 0; i < 4; ++i)
#pragma unroll
    for (int j = 0; j < 4; ++j) acc[i][j] = (f32x4){0.f, 0.f, 0.f, 0.f};
  for (int j0 = 0; j0 < NPIX; j0 += 32) {
#pragma unroll
    for (int s = 0; s < 2; ++s) {
      const int cc = ((tid + 256 * s) >> 7) & 3;
      const int lb = ((tid & ~63) + 256 * s) * 8;
      size_t ga = vbase + j0 + cc * 8;
      async16(vH + ga, &sAh[lb]);
      async16(vL + ga, &sAl[lb]);
    }
#pragma unroll
    for (int it = 0; it < 2; ++it) {
      const int kc = kc0 + 2 * it;
      const float4 fa = *(const float4*)&f[j0 + kc * 8];
      const float4 fb = *(const float4*)&f[j0 + kc * 8 + 4];
      const float fj[8] = {fa.x, fa.y, fa.z, fa.w, fb.x, fb.y, fb.z, fb.w};
      f16x8 ph, plo;
#pragma unroll
      for (int q = 0; q < 8; ++q) {
        float p = __expf(fmaf(av, fj[q], -mv)) * zv;
        f16 h = (f16)p;
        ph[q] = h;
        plo[q] = (f16)(p - (float)h);
      }
      const int off = (kc * 128 + ni_) * 8;
      *(f16x8*)&sPh[off] = ph;
      *(f16x8*)&sPl[off] = plo;
    }
    __syncthreads();
    f16x8 fah[4], fal[4], fbh[4], fbl[4];
#pragma unroll
    for (int mi = 0; mi < 4; ++mi) {
      int ix = (quad * 128 + wm + mi * 16 + mrow) * 8;
      fah[mi] = *(const f16x8*)&sAh[ix];
      fal[mi] = *(const f16x8*)&sAl[ix];
    }
#pragma unroll
    for (int ni = 0; ni < 4; ++ni) {
      int ix = (quad * 128 + wn + ni * 16 + mrow) * 8;
      fbh[ni] = *(const f16x8*)&sPh[ix];
      fbl[ni] = *(const f16x8*)&sPl[ix];
    }
#pragma unroll
    for (int mi = 0; mi < 4; ++mi)
#pragma unroll
      for (int ni = 0; ni < 4; ++ni)
        acc[mi][ni] = __builtin_amdgcn_mfma_f32_16x16x32_f16(fah[mi], fbh[ni], acc[mi][ni], 0, 0, 0);
#pragma unroll
    for (int mi = 0; mi < 4; ++mi)
#pragma unroll
      for (int ni = 0; ni < 4; ++ni)
        acc[mi][ni] = __builtin_amdgcn_mfma_f32_16x16x32_f16(fah[mi], fbl[ni], acc[mi][ni], 0, 0, 0);
#pragma unroll
    for (int mi = 0; mi < 4; ++mi)
#pragma unroll
      for (int ni = 0; ni < 4; ++ni)
        acc[mi][ni] = __builtin_amdgcn_mfma_f32_16x16x32_f16(fal[mi], fbh[ni], acc[mi][ni], 0, 0, 0);
    __syncthreads();
  }
  const float g = gptr[0];
  const float inv = 1.0f / 256.0f;
#pragma unroll
  for (int mi = 0; mi < 4; ++mi) {
    const int cbase = cb + wm + mi * 16 + quad * 4;
#pragma unroll
    for (int ni = 0; ni < 4; ++ni) {
      const int i = ib + wn + ni * 16 + mrow;
      f16x4 hv, lv;
#pragma unroll
      for (int rg = 0; rg < 4; ++rg) {
        float xr = in[((size_t)b * 1025 + cbase + rg) * NPIX + i];
        float sv = 16.f * (g * (acc[mi][ni][rg] * inv) + xr);
        f16 h = (f16)sv;
        hv[rg] = h;
        lv[rg] = (f16)(sv - (float)h);
      }
      size_t o = ((size_t)b * NPIX + i) * 1024 + cbase;
      *(f16x4*)&yH[o] = hv;
      *(f16x4*)&yL[o] = lv;
    }
  }
}

// ---------------- weight split prep: [CO][CI][3][3] -> [9][CO][CI] hi/lo ----

__global__ void rf_wsplit(const float* __restrict__ w, f16* __restrict__ wh,
                          f16* __restrict__ wlo, int CO, int CI) {
  int idx = blockIdx.x * 256 + threadIdx.x;  // co*CI + ci
  if (idx >= CO * CI) return;
  int co = idx / CI, ci = idx - co * CI;
#pragma unroll
  for (int t = 0; t < 9; ++t) {
    float v = 256.0f * w[(size_t)idx * 9 + t];
    f16 h = (f16)v;
    size_t o = ((size_t)t * CO + co) * CI + ci;
    wh[o] = h;
    wlo[o] = (f16)(v - (float)h);
  }
}

// ---------------- MFMA dilated 3x3 conv (implicit GEMM, split fp16) --------

template <int BM, int BN, bool F32OUT>
__global__ __launch_bounds__(256, 2) void rf_mconv(
    const f16* __restrict__ xh, const f16* __restrict__ xl,
    const f16* __restrict__ wh, const f16* __restrict__ wlo,
    const float* __restrict__ bias,
    f16* __restrict__ oh, f16* __restrict__ ol, float* __restrict__ of,
    int CI, int CO) {
  constexpr int ROWS = BM / 64;
  constexpr int TPI = 4096 / BM;
  constexpr int NSA = BM / 64;
  constexpr int NSB = BN / 64;
  __shared__ f16 sAh[BM * 32], sAl[BM * 32], sBh[BN * 32], sBl[BN * 32];
  const int tid = threadIdx.x;
  const int blkpx = blockIdx.x;
  const int cob = blockIdx.y * BN;
  const int b = blkpx / TPI;
  const int h0 = (blkpx - b * TPI) * ROWS;

  const int pA = tid & (BM - 1);
  const int rA = pA >> 6, wpx = pA & 63;
  const int pB = tid & (BN - 1);

  const int wv = tid >> 6, lane = tid & 63;
  const int mrow = lane & 15, quad = lane >> 4;
  const int wm = (BN == 128) ? (wv & 1) * 64 : wv * 64;
  const int wn = (BN == 128) ? (wv >> 1) * 64 : 0;

  f32x4 acc[4][4];
#pragma unroll
  for (int i = 0; i < 4; ++i)
#pragma unroll
    for (int j = 0; j < 4; ++j) acc[i][j] = (f32x4){0.f, 0.f, 0.f, 0.f};

  const int KI = CI >> 5;
  for (int t = 0; t < 9; ++t) {
    const int dh = (t / 3) * 2 - 2, dw = (t - (t / 3) * 3) * 2 - 2;
    const int hin = h0 + rA + dh, win = wpx + dw;
    const bool val = ((unsigned)hin < 64u) && ((unsigned)win < 64u);
    const size_t apix = (((size_t)b * 64 + (val ? hin : 0)) * 64 + (val ? win : 0)) * CI;
#pragma unroll
    for (int s = 0; s < NSA; ++s) {
      int c = tid + 256 * s;
      *(int4*)&sAh[c * 8] = make_int4(0, 0, 0, 0);
      *(int4*)&sAl[c * 8] = make_int4(0, 0, 0, 0);
    }
    __syncthreads();
    const size_t wbase = ((size_t)t * CO + cob + pB) * CI;
    for (int k = 0; k < KI; ++k) {
      const int ci0 = k << 5;
#pragma unroll
      for (int s = 0; s < NSA; ++s) {
        const int cc = ((tid + 256 * s) / BM) & 3;
        const int lb = ((tid & ~63) + 256 * s) * 8;
        if (val) {
          size_t go = apix + ci0 + cc * 8;
          async16(xh + go, &sAh[lb]);
          async16(xl + go, &sAl[lb]);
        }
      }
#pragma unroll
      for (int s = 0; s < NSB; ++s) {
        const int cc = ((tid + 256 * s) / BN) & 3;
        const int lb = ((tid & ~63) + 256 * s) * 8;
        size_t go = wbase + ci0 + cc * 8;
        async16(wh + go, &sBh[lb]);
        async16(wlo + go, &sBl[lb]);
      }
      __syncthreads();
      f16x8 fah[4], fal[4], fbh[4], fbl[4];
#pragma unroll
      for (int mi = 0; mi < 4; ++mi) {
        int ix = (quad * BM + wm + mi * 16 + mrow) * 8;
        fah[mi] = *(const f16x8*)&sAh[ix];
        fal[mi] = *(const f16x8*)&sAl[ix];
      }
#pragma unroll
      for (int ni = 0; ni < 4; ++ni) {
        int ix = (quad * BN + wn + ni * 16 + mrow) * 8;
        fbh[ni] = *(const f16x8*)&sBh[ix];
        fbl[ni] = *(const f16x8*)&sBl[ix];
      }
#pragma unroll
      for (int mi = 0; mi < 4; ++mi)
#pragma unroll
        for (int ni = 0; ni < 4; ++ni)
          acc[mi][ni] = __builtin_amdgcn_mfma_f32_16x16x32_f16(fah[mi], fbh[ni], acc[mi][ni], 0, 0, 0);
#pragma unroll
      for (int mi = 0; mi < 4; ++mi)
#pragma unroll
        for (int ni = 0; ni < 4; ++ni)
          acc[mi][ni] = __builtin_amdgcn_mfma_f32_16x16x32_f16(fah[mi], fbl[ni], acc[mi][ni], 0, 0, 0);
#pragma unroll
      for (int mi = 0; mi < 4; ++mi)
#pragma unroll
        for (int ni = 0; ni < 4; ++ni)
          acc[mi][ni] = __builtin_amdgcn_mfma_f32_16x16x32_f16(fal[mi], fbh[ni], acc[mi][ni], 0, 0, 0);
      __syncthreads();
    }
  }
  const float inv = 1.0f / 4096.0f;
  float bvs[4];
#pragma unroll
  for (int ni = 0; ni < 4; ++ni) bvs[ni] = bias[cob + wn + ni * 16 + mrow];
#pragma unroll
  for (int mi = 0; mi < 4; ++mi) {
#pragma unroll
    for (int rg = 0; rg < 4; ++rg) {
      int px = wm + mi * 16 + quad * 4 + rg;
      int hh = h0 + (px >> 6), wwp = px & 63;
#pragma unroll
      for (int ni = 0; ni < 4; ++ni) {
        int co = cob + wn + ni * 16 + mrow;
        float vv = fmaxf(acc[mi][ni][rg] * inv + bvs[ni], 0.f);
        if (F32OUT) {
          of[(((size_t)b * CO + co) * 64 + hh) * 64 + wwp] = vv;
        } else {
          float sv = vv * 16.f;
          f16 hv = (f16)sv;
          size_t o = (((size_t)b * 64 + hh) * 64 + wwp) * CO + co;
          oh[o] = hv;
          ol[o] = (f16)(sv - (float)hv);
        }
      }
    }
  }
}

// ---------------- scan weight frag prep: w[64][64][9] -> frag order ---------
// fh[(((w4*9 + t)*2 + kc)*64 + lane)*8 + j] = f16(256*w[co][ci][t]) where
// co = 16*w4 + (lane&15), ci = kc*32 + (lane>>4)*8 + j.

__global__ void rf_wfrag(const float* __restrict__ w, f16* __restrict__ fh,
                         f16* __restrict__ fl) {
  int gid = blockIdx.x * 256 + threadIdx.x;
  if (gid >= 4608) return;
  int lane = gid & 63;
  int rem = gid >> 6;
  int kc = rem & 1;
  int rem2 = rem >> 1;
  int t = rem2 % 9;
  int w4 = rem2 / 9;
  int co = w4 * 16 + (lane & 15);
  int cib = kc * 32 + (lane >> 4) * 8;
  f16x8 hb, lb;
#pragma unroll
  for (int j = 0; j < 8; ++j) {
    float v = 256.f * w[((size_t)co * 64 + cib + j) * 9 + t];
    f16 h = (f16)v;
    hb[j] = h;
    lb[j] = (f16)(v - (float)h);
  }
  *(f16x8*)&fh[(size_t)gid * 8] = hb;
  *(f16x8*)&fl[(size_t)gid * 8] = lb;
}

// ---------------- MFMA recurrent scan (conv1d k=9 pad 4, 63 steps) ---------
// 1 block/batch, 4 waves.  Wave w owns co [16w,16w+16), all 64 pos.
// Carry in LDS [rowIdx = pos+4][ci] hi/lo f16, XOR-granule swizzle:
// addr = rowIdx*64 + ((ci>>3)^(rowIdx&7))*8 + (ci&7).  Rows 0..3,68..71 = 0.
// out = relu(conv/256 + bias) + src_row; dst row = out; carry = out.

__global__ __launch_bounds__(256, 1) void rf_mscan(
    const float* __restrict__ src, float* __restrict__ dst,
    const f16* __restrict__ fh, const f16* __restrict__ fl,
    const float* __restrict__ bias, int dir) {
  __shared__ f16 ch[72 * 64], cl_[72 * 64];
  const int b = blockIdx.x;
  const int tid = threadIdx.x;
  const int wave = tid >> 6, lane = tid & 63;
  const int quad = lane >> 4, l15 = lane & 15;

  // A frags (static weights) -> registers
  f16x8 Ah[9][2], Al[9][2];
#pragma unroll
  for (int t = 0; t < 9; ++t)
#pragma unroll
    for (int kc = 0; kc < 2; ++kc) {
      int ix = (((wave * 9 + t) * 2 + kc) * 64 + lane) * 8;
      Ah[t][kc] = *(const f16x8*)&fh[ix];
      Al[t][kc] = *(const f16x8*)&fl[ix];
    }
  float bvs[4];
#pragma unroll
  for (int r = 0; r < 4; ++r) bvs[r] = bias[wave * 16 + quad * 4 + r];

  // zero carry (incl. pad rows)
  for (int s = tid; s < 2304; s += 256) {
    ((unsigned*)ch)[s] = 0u;
    ((unsigned*)cl_)[s] = 0u;
  }
  __syncthreads();

  const size_t sbase = (size_t)b * 64 * 4096;
  const int row0 = (dir > 0) ? 0 : 63;
  {
    int pos0 = tid & 63, cig = tid >> 6;
#pragma unroll
    for (int q = 0; q < 16; ++q) {
      int ci = cig * 16 + q;
      float v = src[sbase + (size_t)ci * 4096 + row0 * 64 + pos0];
      dst[sbase + (size_t)ci * 4096 + row0 * 64 + pos0] = v;
      f16 h = (f16)v;
      int rowIdx = pos0 + 4;
      int addr = rowIdx * 64 + (((ci >> 3) ^ (rowIdx & 7)) << 3) + (ci & 7);
      ch[addr] = h;
      cl_[addr] = (f16)(v - (float)h);
    }
  }
  __syncthreads();

  const float inv = 1.0f / 256.0f;
  for (int s = 1; s < 64; ++s) {
    const int row = (dir > 0) ? s : 63 - s;
    // prefetch src row (independent of MFMA phase)
    float srow[4][4];
#pragma unroll
    for (int nt = 0; nt < 4; ++nt)
#pragma unroll
      for (int r = 0; r < 4; ++r)
        srow[nt][r] = src[sbase + (size_t)(wave * 16 + quad * 4 + r) * 4096 +
                          row * 64 + nt * 16 + l15];
    f32x4 acc[4];
#pragma unroll
    for (int nt = 0; nt < 4; ++nt) acc[nt] = (f32x4){0.f, 0.f, 0.f, 0.f};
#pragma unroll
    for (int t = 0; t < 9; ++t)
#pragma unroll
      for (int kc = 0; kc < 2; ++kc) {
#pragma unroll
        for (int nt = 0; nt < 4; ++nt) {
          int rowIdx = nt * 16 + l15 + t;
          int gr = kc * 4 + quad;
          int addr = rowIdx * 64 + ((gr ^ (rowIdx & 7)) << 3);
          f16x8 Bh = *(const f16x8*)&ch[addr];
          f16x8 Bl = *(const f16x8*)&cl_[addr];
          acc[nt] = __builtin_amdgcn_mfma_f32_16x16x32_f16(Ah[t][kc], Bh, acc[nt], 0, 0, 0);
          acc[nt] = __builtin_amdgcn_mfma_f32_16x16x32_f16(Al[t][kc], Bh, acc[nt], 0, 0, 0);
          acc[nt] = __builtin_amdgcn_mfma_f32_16x16x32_f16(Ah[t][kc], Bl, acc[nt], 0, 0, 0);
        }
      }
    __syncthreads();  // all reads of carry done
#pragma unroll
    for (int nt = 0; nt < 4; ++nt) {
      int pos = nt * 16 + l15;
      int rowIdx = pos + 4;
      f16x4 hv, lv;
#pragma unroll
      for (int r = 0; r < 4; ++r) {
        float v = fmaxf(acc[nt][r] * inv + bvs[r], 0.f) + srow[nt][r];
        dst[sbase + (size_t)(wave * 16 + quad * 4 + r) * 4096 + row * 64 + pos] = v;
        f16 h = (f16)v;
        hv[r] = h;
        lv[r] = (f16)(v - (float)h);
      }
      int ci0 = wave * 16 + quad * 4;
      int addr = rowIdx * 64 + (((ci0 >> 3) ^ (rowIdx & 7)) << 3) + (ci0 & 7);
      *(f16x4*)&ch[addr] = hv;
      *(f16x4*)&cl_[addr] = lv;
    }
    __syncthreads();  // carry fully updated
  }
}

// ---------------- transpose last two dims (64x64) per (b,c) ----------------

__global__ void rf_transpose(const float* __restrict__ src, float* __restrict__ dst) {
  int bc = blockIdx.x;  // 256
  __shared__ float tl[64][65];
  int tid = threadIdx.x;
  const float* sp = src + (size_t)bc * 4096;
  float* dp = dst + (size_t)bc * 4096;
  for (int s = tid; s < 4096; s += 256) {
    int h = s >> 6, w = s & 63;
    tl[w][h] = sp[s];
  }
  __syncthreads();
  for (int s = tid; s < 4096; s += 256) dp[s] = tl[s >> 6][s & 63];
}

// ---------------- final 1x1 conv + relu + 8x8 upsample ----------------

__global__ void rf_final(const float* __restrict__ t, const float* __restrict__ ow,
                         const float* __restrict__ ob, float* __restrict__ out) {
  int b = blockIdx.y;
  int s = blockIdx.x * 256 + threadIdx.x;  // 0..4095
  int w = s >> 6, h = s & 63;
  float acc = ob[0];
  for (int c = 0; c < 64; ++c)
    acc += ow[c] * t[(((size_t)b * 64 + c) * 64 + w) * 64 + h];
  acc = fmaxf(acc, 0.f);
  float4 vv = make_float4(acc, acc, acc, acc);
  for (int dy = 0; dy < 8; ++dy) {
    float* dp = out + ((size_t)b * 512 + h * 8 + dy) * 512 + w * 8;
    *(float4*)dp = vv;
    *(float4*)(dp + 4) = vv;
  }
}

// ---------------- launch ----------------

extern "C" void kernel_launch(void* const* d_in, const int* in_sizes, int n_in,
                              void* d_out, int out_size, void* d_ws, size_t ws_size,
                              hipStream_t stream) {
  const float* in    = (const float*)d_in[0];
  const float* wA    = (const float*)d_in[1];
  const float* bA    = (const float*)d_in[2];
  const float* wB    = (const float*)d_in[3];
  const float* wC    = (const float*)d_in[5];
  const float* bC    = (const float*)d_in[6];
  const float* gamma = (const float*)d_in[7];
  const float* bw1 = (const float*)d_in[8];  const float* bb1 = (const float*)d_in[9];
  const float* bw2 = (const float*)d_in[10]; const float* bb2 = (const float*)d_in[11];
  const float* bw3 = (const float*)d_in[12]; const float* bb3 = (const float*)d_in[13];
  const float* bw4 = (const float*)d_in[14]; const float* bb4 = (const float*)d_in[15];
  const float* bw5 = (const float*)d_in[16]; const float* bb5 = (const float*)d_in[17];
  const float* bw6 = (const float*)d_in[18]; const float* bb6 = (const float*)d_in[19];
  const float* du_w = (const float*)d_in[20]; const float* du_b = (const float*)d_in[21];
  const float* lr_w = (const float*)d_in[22]; const float* lr_b = (const float*)d_in[23];
  const float* ow   = (const float*)d_in[24]; const float* ob   = (const float*)d_in[25];
  float* out = (float*)d_out;
  float* ws = (float*)d_ws;

  // phase-1 buffers
  f16* vH  = (f16*)(ws + 0);
  f16* vL  = (f16*)(ws + 8388608);
  f16* xTh = (f16*)(ws + 16777216);
  f16* wCh = (f16*)(ws + 25165824);
  f16* wCl = (f16*)(ws + 25690112);
  f16* yH  = (f16*)(ws + 16777216);
  f16* yL  = (f16*)(ws + 25165824);
  // conv phase
  f16* w1h = (f16*)(ws + 0);        f16* w1l = (f16*)(ws + 2359296);
  f16* c1H = (f16*)(ws + 4718592);  f16* c1L = (f16*)(ws + 8912896);
  f16* w3h = (f16*)(ws + 13107200); f16* w3l = (f16*)(ws + 14286848);
  f16* w2h = (f16*)(ws + 16777216); f16* w2l = (f16*)(ws + 17956864);
  f16* c2H = (f16*)(ws + 19136512); f16* c2L = (f16*)(ws + 23330816);
  f16* w4h = (f16*)(ws + 27525120); f16* w4l = (f16*)(ws + 28114944);
  f16* c4H = (f16*)(ws + 28704768); f16* c4L = (f16*)(ws + 30801920);
  f16* c3H = c1H;                   f16* c3L = c1L;
  f16* w5h = (f16*)(ws + 0);        f16* w5l = (f16*)(ws + 147456);
  f16* c5H = (f16*)(ws + 294912);   f16* c5L = (f16*)(ws + 1343488);
  f16* w6h = (f16*)(ws + 2392064);  f16* w6l = (f16*)(ws + 2428928);
  float* tin = ws + 4718592;
  float* t0  = ws + 5767168;
  float* t1  = ws + 6815744;
  // scan weight frags (dead c1/c3 zone, after mconv4)
  f16* duFh = (f16*)(ws + 7864320);
  f16* duFl = (f16*)(ws + 7882752);
  f16* lrFh = (f16*)(ws + 7901184);
  f16* lrFl = (f16*)(ws + 7919616);
  float* sm = ws + 33554432;
  float* A_  = sm;
  float* M_  = sm + 16384;
  float* iZ  = sm + 32768;
  float* u_  = sm + 49152;
  float* s_  = sm + 50176;
  float* c0_ = sm + 50304;
  float* fst = sm + 50308;

  rf_s<<<1, 128, 0, stream>>>(wB, bA, s_, c0_);
  rf_u<<<4, 256, 0, stream>>>(wA, s_, u_);
  rf_fstat<<<4, 256, 0, stream>>>(in, fst);
  rf_A<<<dim3(16, 4), 256, 0, stream>>>(in, u_, c0_, fst, A_, M_);
  rf_Z<<<4096, 256, 0, stream>>>(in, A_, M_, iZ);
  rf_xsplit<<<dim3(64, 16, 4), 256, 0, stream>>>(in, xTh);
  rf_wCsplit<<<512, 256, 0, stream>>>(wC, wCh, wCl);
  rf_vgemmm<<<dim3(32, 8, 4), 256, 0, stream>>>(wCh, wCl, xTh, bC, vH, vL);
  rf_attm<<<dim3(32, 8, 4), 256, 0, stream>>>(vH, vL, A_, M_, iZ, in, gamma, yH, yL);

  rf_wsplit<<<2048, 256, 0, stream>>>(bw1, w1h, w1l, 512, 1024);
  rf_wsplit<<<1024, 256, 0, stream>>>(bw3, w3h, w3l, 512, 512);
  rf_mconv<128, 128, false><<<dim3(128, 4), 256, 0, stream>>>(
      yH, yL, w1h, w1l, bb1, c1H, c1L, nullptr, 1024, 512);
  rf_wsplit<<<1024, 256, 0, stream>>>(bw2, w2h, w2l, 512, 512);
  rf_wsplit<<<512, 256, 0, stream>>>(bw4, w4h, w4l, 256, 512);
  rf_wsplit<<<128, 256, 0, stream>>>(bw5, w5h, w5l, 128, 256);
  rf_wsplit<<<32, 256, 0, stream>>>(bw6, w6h, w6l, 64, 128);
  rf_mconv<128, 128, false><<<dim3(128, 4), 256, 0, stream>>>(
      c1H, c1L, w2h, w2l, bb2, c2H, c2L, nullptr, 512, 512);
  rf_mconv<128, 128, false><<<dim3(128, 4), 256, 0, stream>>>(
      c2H, c2L, w3h, w3l, bb3, c3H, c3L, nullptr, 512, 512);
  rf_mconv<128, 128, false><<<dim3(128, 2), 256, 0, stream>>>(
      c3H, c3L, w4h, w4l, bb4, c4H, c4L, nullptr, 512, 256);
  // c1/c3 region now dead -> scan weight frags
  rf_wfrag<<<18, 256, 0, stream>>>(du_w, duFh, duFl);
  rf_wfrag<<<18, 256, 0, stream>>>(lr_w, lrFh, lrFl);
  rf_mconv<128, 128, false><<<dim3(128, 1), 256, 0, stream>>>(
      c4H, c4L, w5h, w5l, bb5, c5H, c5L, nullptr, 256, 128);
  rf_mconv<256, 64, true><<<dim3(64, 1), 256, 0, stream>>>(
      c5H, c5L, w6h, w6l, bb6, nullptr, nullptr, tin, 128, 64);

  rf_mscan<<<4, 256, 0, stream>>>(tin, t0, duFh, duFl, du_b, +1);
  rf_mscan<<<4, 256, 0, stream>>>(t0, t1, duFh, duFl, du_b, -1);
  rf_transpose<<<256, 256, 0, stream>>>(t1, t0);
  rf_mscan<<<4, 256, 0, stream>>>(t0, t1, lrFh, lrFl, lr_b, +1);
  rf_mscan<<<4, 256, 0, stream>>>(t1, t0, lrFh, lrFl, lr_b, -1);
  rf_final<<<dim3(16, 4), 256, 0, stream>>>(t0, ow, ob, out);
}